// Round 1
// baseline (2186.818 us; speedup 1.0000x reference)
//
#include <hip/hip_runtime.h>

typedef unsigned short u16;
typedef unsigned int   u32;
typedef short bf16x8 __attribute__((ext_vector_type(8)));
typedef float f32x4  __attribute__((ext_vector_type(4)));

#define NTOK 4096   // B*S
#define SEQ  1024

__device__ __forceinline__ u16 f2bf(float f){
  union { float f; u32 u; } x; x.f = f;
  u32 r = (x.u + 0x7FFFu + ((x.u >> 16) & 1u)) >> 16;
  return (u16)r;
}
__device__ __forceinline__ float bf2f(u16 u){
  union { u32 u; float f; } x; x.u = ((u32)u) << 16; return x.f;
}
__device__ __forceinline__ void gl_lds16(const void* gp, void* lp){
  __builtin_amdgcn_global_load_lds(
      (const __attribute__((address_space(1))) u32*)gp,
      (__attribute__((address_space(3))) u32*)lp, 16, 0, 0);
}

// ---------------------------------------------------------------- converts
__global__ __launch_bounds__(256) void conv_x(const float* __restrict__ x,
                                              u16* __restrict__ xs, float* __restrict__ xt){
  int t = blockIdx.x * 256 + threadIdx.x;        // < NTOK*1024
  int tok = t >> 10, i = t & 1023;
  xs[t] = f2bf(x[(size_t)tok * 1025 + 1 + i]);
  if (i == 0) xt[tok] = x[(size_t)tok * 1025];
}

__global__ __launch_bounds__(256) void conv_w(const float* __restrict__ W,
                                              u16* __restrict__ Wb, float* __restrict__ w0, int shift){
  int t = blockIdx.x * 256 + threadIdx.x;        // < rows<<shift (exact grid)
  int Kin = 1 << shift;
  int r = t >> shift, i = t & (Kin - 1);
  Wb[t] = f2bf(W[(size_t)r * (Kin + 1) + 1 + i]);
  if (i == 0) w0[r] = W[(size_t)r * (Kin + 1)];
}

// ---------------------------------------------------------------- row/head times
__global__ __launch_bounds__(256) void head_time(const u16* __restrict__ src, float* __restrict__ dst){
  int g = blockIdx.x * 4 + (threadIdx.x >> 6);   // (b*16+h)*1024 + s, < 65536
  int l = threadIdx.x & 63;
  int b = g >> 14, h = (g >> 10) & 15, s = g & 1023;
  float v = bf2f(src[((size_t)(b * 1024 + s)) * 3072 + h * 64 + l]);
  float ss = v * v;
  for (int m = 1; m < 64; m <<= 1) ss += __shfl_xor(ss, m, 64);
  if (l == 0) dst[g] = sqrtf(ss + 1.f);
}

__global__ __launch_bounds__(256) void row_time(const u16* __restrict__ src, float* __restrict__ dst, int L){
  int g = blockIdx.x * 4 + (threadIdx.x >> 6);   // token
  int l = threadIdx.x & 63;
  const u16* r = src + (size_t)g * L;
  float ss = 0.f;
  for (int j = l; j < L; j += 64){ float v = bf2f(r[j]); ss += v * v; }
  for (int m = 1; m < 64; m <<= 1) ss += __shfl_xor(ss, m, 64);
  if (l == 0) dst[g] = sqrtf(ss + 1.f);
}

// ---------------------------------------------------------------- V transpose (+ time row)
// out: vT[(bh*65 + r)*1024 + key]; r=0 is t_v, r=1..64 are feats 0..63
__global__ __launch_bounds__(256) void v_transpose(const u16* __restrict__ qkv, u16* __restrict__ vT){
  __shared__ u16 tile[64 * 72];
  __shared__ float tvsq[64];
  const int tid = threadIdx.x;
  const int kt = blockIdx.x, bh = blockIdx.y;
  const int b = bh >> 4, h = bh & 15;
  if (tid < 64) tvsq[tid] = 0.f;
  __syncthreads();
  for (int i = 0; i < 2; i++){
    int c = tid * 2 + i;                          // 0..511
    int key = c >> 3, fc = c & 7;
    union { uint4 v; u16 s[8]; } d;
    d.v = *(const uint4*)(qkv + ((size_t)(b * 1024 + kt * 64 + key)) * 3072 + 2048 + h * 64 + fc * 8);
    *(uint4*)&tile[key * 72 + fc * 8] = d.v;
    float ss = 0.f;
    for (int j = 0; j < 8; j++){ float v = bf2f(d.s[j]); ss += v * v; }
    atomicAdd(&tvsq[key], ss);
  }
  __syncthreads();
  for (int c = tid; c < 520; c += 256){
    int vtr = c >> 3, kc = c & 7;
    union { uint4 v; u16 s[8]; } d;
    if (vtr == 0){
      for (int j = 0; j < 8; j++) d.s[j] = f2bf(sqrtf(tvsq[kc * 8 + j] + 1.f));
    } else {
      int f = vtr - 1;
      for (int j = 0; j < 8; j++) d.s[j] = tile[(kc * 8 + j) * 72 + f];
    }
    *(uint4*)(vT + ((size_t)bh * 65 + vtr) * 1024 + kt * 64 + kc * 8) = d.v;
  }
}

// ---------------------------------------------------------------- GEMM: C = A(MxK) * B(NxK)^T + at[m]*b0[n] + bias[n]
// mode 0: bf16 out, bias segmented q/k/v ; mode 1: f32 out ; mode 2: relu -> bf16 out
__global__ __launch_bounds__(256) void gemm_bt(
    const u16* __restrict__ A, int lda, const u16* __restrict__ Bm, int ldb,
    const float* __restrict__ at, const float* __restrict__ b0,
    const float* __restrict__ bias_a, const float* __restrict__ bias_b, const float* __restrict__ bias_c,
    float* __restrict__ Cf, u16* __restrict__ Cbf, int ldc, int K, int mode)
{
  __shared__ u16 As[128 * 32];
  __shared__ u16 Bs[128 * 32];
  const int tid = threadIdx.x;
  const int w = tid >> 6, l = tid & 63;
  const int l15 = l & 15, q = l >> 4;
  const int m0 = blockIdx.y * 128, n0 = blockIdx.x * 128;
  const int wr = w >> 1, wc = w & 1;
  f32x4 acc[4][4] = {};
  for (int kt = 0; kt < K; kt += 32){
    __syncthreads();
    for (int i = 0; i < 2; i++){
      int c = (w * 2 + i) * 64 + l;               // chunk: row=c>>2, kc=c&3
      gl_lds16(A  + (size_t)(m0 + (c >> 2)) * lda + kt + (c & 3) * 8, &As[(w * 2 + i) * 512]);
      gl_lds16(Bm + (size_t)(n0 + (c >> 2)) * ldb + kt + (c & 3) * 8, &Bs[(w * 2 + i) * 512]);
    }
    __syncthreads();
    bf16x8 af[4], bfr[4];
    for (int i = 0; i < 4; i++){
      int row = wr * 64 + i * 16 + l15;
      af[i] = *(const bf16x8*)&As[(row * 4 + q) * 8];
    }
    for (int j = 0; j < 4; j++){
      int row = wc * 64 + j * 16 + l15;
      bfr[j] = *(const bf16x8*)&Bs[(row * 4 + q) * 8];
    }
    for (int i = 0; i < 4; i++)
      for (int j = 0; j < 4; j++)
        acc[i][j] = __builtin_amdgcn_mfma_f32_16x16x32_bf16(af[i], bfr[j], acc[i][j], 0, 0, 0);
  }
  for (int i = 0; i < 4; i++){
    float atv[4];
    for (int r = 0; r < 4; r++) atv[r] = at[m0 + wr * 64 + i * 16 + q * 4 + r];
    for (int j = 0; j < 4; j++){
      int col = n0 + wc * 64 + j * 16 + l15;
      float b0v = b0[col];
      float bv;
      if (mode == 0) bv = (col < 1024) ? bias_a[col] : (col < 2048) ? bias_b[col - 1024] : bias_c[col - 2048];
      else bv = bias_a[col];
      for (int r = 0; r < 4; r++){
        size_t row = (size_t)(m0 + wr * 64 + i * 16 + q * 4 + r);
        float v = acc[i][j][r] + atv[r] * b0v + bv;
        if (mode == 2) v = fmaxf(v, 0.f);
        if (mode == 1) Cf[row * ldc + col] = v;
        else           Cbf[row * ldc + col] = f2bf(v);
      }
    }
  }
}

// ---------------------------------------------------------------- flash attention
// grid (S/64, B*H); 4 waves, wave w owns 16 q-rows; online softmax (no l needed:
// lorentz normalize is scale-invariant)
__global__ __launch_bounds__(256) void attn_kernel(
    const u16* __restrict__ qkv, const float* __restrict__ qt,
    const float* __restrict__ ktm, const u16* __restrict__ vT,
    u16* __restrict__ aout)
{
  __shared__ u16 Qlds[4096];
  __shared__ u16 Klds[4096];
  __shared__ u16 Vlds[5120];   // 80 rows x 8 chunks (rows 65..79 garbage, unused cols)
  __shared__ u16 Plds[4608];   // 4 waves x 16 x 72
  const int tid = threadIdx.x;
  const int w = tid >> 6, l = tid & 63;
  const int l15 = l & 15, qd = l >> 4;
  const int q0 = blockIdx.x * 64;
  const int bh = blockIdx.y;
  const int b = bh >> 4, h = bh & 15;
  const size_t tokbase = (size_t)b << 10;

  for (int i = 0; i < 2; i++){
    int s = (w * 2 + i) * 64 + l;
    int row = s >> 3, kc = ((s & 7) - row) & 7;   // rotation: chunk(row,kc) -> slot row*8+((kc+row)&7)
    gl_lds16(qkv + (tokbase + q0 + row) * 3072 + h * 64 + kc * 8, &Qlds[(w * 2 + i) * 512]);
  }
  __syncthreads();
  bf16x8 aq[2];
  {
    int row = w * 16 + l15;
    for (int kk = 0; kk < 2; kk++)
      aq[kk] = *(const bf16x8*)&Qlds[(row * 8 + ((kk * 4 + qd + row) & 7)) * 8];
  }
  float tq[4];
  for (int r = 0; r < 4; r++)
    tq[r] = qt[(size_t)bh * SEQ + q0 + w * 16 + qd * 4 + r];

  float mrow[4] = {-1e30f, -1e30f, -1e30f, -1e30f};
  f32x4 acco[5] = {};

  for (int kt = 0; kt < 16; kt++){
    __syncthreads();
    for (int i = 0; i < 2; i++){
      int s = (w * 2 + i) * 64 + l;
      int row = s >> 3, kc = ((s & 7) - row) & 7;
      gl_lds16(qkv + (tokbase + kt * 64 + row) * 3072 + 1024 + h * 64 + kc * 8, &Klds[(w * 2 + i) * 512]);
      gl_lds16(vT + ((size_t)bh * 65 + row) * 1024 + kt * 64 + kc * 8, &Vlds[(w * 2 + i) * 512]);
    }
    if (w == 0 && l < 8){                          // vT row 64 (feat 63): slots 512..519
      gl_lds16(vT + ((size_t)bh * 65 + 64) * 1024 + kt * 64 + (l & 7) * 8, &Vlds[4096]);
    }
    __syncthreads();

    float sc[4][4];
    float mx[4] = {-1e30f, -1e30f, -1e30f, -1e30f};
    for (int ct = 0; ct < 4; ct++){
      f32x4 z = {0.f, 0.f, 0.f, 0.f};
      int key = ct * 16 + l15;
      for (int kk = 0; kk < 2; kk++){
        bf16x8 bk = *(const bf16x8*)&Klds[(key * 8 + ((kk * 4 + qd + key) & 7)) * 8];
        z = __builtin_amdgcn_mfma_f32_16x16x32_bf16(aq[kk], bk, z, 0, 0, 0);
      }
      float tk = ktm[(size_t)bh * SEQ + kt * 64 + key];
      for (int r = 0; r < 4; r++){
        float s = 0.25f + 0.25f * (z[r] - tq[r] * tk);
        sc[ct][r] = s;
        mx[r] = fmaxf(mx[r], s);
      }
    }
    for (int r = 0; r < 4; r++){
      for (int msk = 1; msk < 16; msk <<= 1)
        mx[r] = fmaxf(mx[r], __shfl_xor(mx[r], msk, 64));
      float mnew = fmaxf(mrow[r], mx[r]);
      float alpha = __expf(mrow[r] - mnew);
      mrow[r] = mnew;
      for (int co = 0; co < 5; co++) acco[co][r] *= alpha;
      mx[r] = mnew;
    }
    for (int ct = 0; ct < 4; ct++)
      for (int r = 0; r < 4; r++)
        Plds[w * 1152 + (qd * 4 + r) * 72 + ct * 16 + l15] = f2bf(__expf(sc[ct][r] - mx[r]));
    asm volatile("s_waitcnt lgkmcnt(0)" ::: "memory");
    bf16x8 ap[2];
    for (int kk = 0; kk < 2; kk++)
      ap[kk] = *(const bf16x8*)&Plds[w * 1152 + l15 * 72 + kk * 32 + qd * 8];
    for (int co = 0; co < 5; co++){
      int vtr = co * 16 + l15;
      for (int kk = 0; kk < 2; kk++){
        bf16x8 bv = *(const bf16x8*)&Vlds[(vtr * 8 + ((kk * 4 + qd + vtr) & 7)) * 8];
        acco[co] = __builtin_amdgcn_mfma_f32_16x16x32_bf16(ap[kk], bv, acco[co], 0, 0, 0);
      }
    }
  }
  for (int r = 0; r < 4; r++){
    float ss = 0.f;
    for (int co = 0; co < 5; co++){
      int col = co * 16 + l15;
      float v = acco[co][r];
      if (col == 0) ss -= v * v;
      else if (col < 65) ss += v * v;
    }
    for (int msk = 1; msk < 16; msk <<= 1) ss += __shfl_xor(ss, msk, 64);
    float rn = rsqrtf(fmaxf(fabsf(ss), 1e-8f));
    size_t rowg = tokbase + q0 + w * 16 + qd * 4 + r;
    for (int co = 0; co < 5; co++){
      int col = co * 16 + l15;
      if (col >= 1 && col < 65)
        aout[rowg * 1024 + h * 64 + col - 1] = f2bf(acco[co][r] * rn);
    }
  }
}

// ---------------------------------------------------------------- midpoint + hyp_layernorm
__device__ __forceinline__ float block_sum(float v, float* red){
  int tid = threadIdx.x;
  for (int m = 1; m < 64; m <<= 1) v += __shfl_xor(v, m, 64);
  __syncthreads();
  if ((tid & 63) == 0) red[tid >> 6] = v;
  __syncthreads();
  return red[0] + red[1] + red[2] + red[3];
}

__global__ __launch_bounds__(256) void mid_ln(
    const float* __restrict__ z, const float* __restrict__ xfull,
    const float* __restrict__ xs, const float* __restrict__ xtv,
    const float* __restrict__ gam, const float* __restrict__ bet,
    float* __restrict__ of, u16* __restrict__ ob, float* __restrict__ ot,
    float* __restrict__ ofull, int mode_x, int mode_out)
{
  __shared__ float red[4];
  const int tid = threadIdx.x;
  const int tok = blockIdx.x;
  const float* zr = z + (size_t)tok * 1024;
  float zv[4], xv[4], xtime;
  if (mode_x == 0){
    const float* xr = xfull + (size_t)tok * 1025;
    xtime = xr[0];
    for (int j = 0; j < 4; j++) xv[j] = xr[1 + tid + j * 256];
  } else {
    xtime = xtv[tok];
    const float* xr = xs + (size_t)tok * 1024;
    for (int j = 0; j < 4; j++) xv[j] = xr[tid + j * 256];
  }
  float ssz = 0.f;
  for (int j = 0; j < 4; j++){ zv[j] = zr[tid + j * 256]; ssz += zv[j] * zv[j]; }
  ssz = block_sum(ssz, red);
  float tz = sqrtf(ssz + 1.f);
  float av[4]; float ssa = 0.f;
  for (int j = 0; j < 4; j++){ av[j] = 0.5f * (zv[j] + xv[j]); ssa += av[j] * av[j]; }
  ssa = block_sum(ssa, red);
  float avt = 0.5f * (tz + xtime);
  float rn = rsqrtf(fmaxf(fabsf(ssa - avt * avt), 1e-8f));
  float uv[4]; float su = 0.f, squ = 0.f;
  for (int j = 0; j < 4; j++){ uv[j] = av[j] * rn; su += uv[j]; squ += uv[j] * uv[j]; }
  su = block_sum(su, red);
  squ = block_sum(squ, red);
  float mu = su * (1.f / 1024.f);
  float var = squ * (1.f / 1024.f) - mu * mu;
  float rv = rsqrtf(fmaxf(var, 0.f) + 1e-5f);
  float sv[4]; float sss = 0.f;
  for (int j = 0; j < 4; j++){
    int i = tid + j * 256;
    sv[j] = (uv[j] - mu) * rv * gam[i] + bet[i];
    sss += sv[j] * sv[j];
  }
  sss = block_sum(sss, red);
  float tout = sqrtf(sss + 1.f);
  if (mode_out == 0){
    for (int j = 0; j < 4; j++){
      int i = tid + j * 256;
      of[(size_t)tok * 1024 + i] = sv[j];
      ob[(size_t)tok * 1024 + i] = f2bf(sv[j]);
    }
    if (tid == 0) ot[tok] = tout;
  } else {
    float* orow = ofull + (size_t)tok * 1025;
    for (int j = 0; j < 4; j++) orow[1 + tid + j * 256] = sv[j];
    if (tid == 0) orow[0] = tout;
  }
}

// ---------------------------------------------------------------- launch
extern "C" void kernel_launch(void* const* d_in, const int* in_sizes, int n_in,
                              void* d_out, int out_size, void* d_ws, size_t ws_size,
                              hipStream_t stream){
  const float* x   = (const float*)d_in[0];
  const float* Wq  = (const float*)d_in[1];
  const float* bq  = (const float*)d_in[2];
  const float* Wk  = (const float*)d_in[3];
  const float* bk  = (const float*)d_in[4];
  const float* Wv  = (const float*)d_in[5];
  const float* bv  = (const float*)d_in[6];
  const float* Wo  = (const float*)d_in[7];
  const float* bo  = (const float*)d_in[8];
  const float* g1  = (const float*)d_in[9];
  const float* be1 = (const float*)d_in[10];
  const float* W1  = (const float*)d_in[11];
  const float* c1  = (const float*)d_in[12];
  const float* W2  = (const float*)d_in[13];
  const float* c2  = (const float*)d_in[14];
  const float* g2  = (const float*)d_in[15];
  const float* be2 = (const float*)d_in[16];
  float* out = (float*)d_out;

  char* p = (char*)d_ws;
  auto take = [&](size_t n){ char* r = p; p += (n + 255) & ~(size_t)255; return r; };
  u16*   xs    = (u16*)  take((size_t)NTOK * 1024 * 2);
  float* xt    = (float*)take(NTOK * 4);
  u16*   wqkv  = (u16*)  take((size_t)3072 * 1024 * 2);
  float* wqkv0 = (float*)take(3072 * 4);
  u16*   wo_s  = (u16*)  take((size_t)1024 * 1024 * 2);
  float* wo0   = (float*)take(1024 * 4);
  u16*   w1_s  = (u16*)  take((size_t)4096 * 1024 * 2);
  float* w10   = (float*)take(4096 * 4);
  u16*   w2_s  = (u16*)  take((size_t)1024 * 4096 * 2);
  float* w20   = (float*)take(1024 * 4);
  u16*   qkvb  = (u16*)  take((size_t)NTOK * 3072 * 2);
  float* qtv   = (float*)take((size_t)64 * 1024 * 4);
  float* ktv   = (float*)take((size_t)64 * 1024 * 4);
  u16*   vT    = (u16*)  take((size_t)64 * 65 * 1024 * 2);
  u16*   aoutb = (u16*)  take((size_t)NTOK * 1024 * 2);
  float* aot   = (float*)take(NTOK * 4);
  float* zbuf  = (float*)take((size_t)NTOK * 1024 * 4);
  float* x1f   = (float*)take((size_t)NTOK * 1024 * 4);
  u16*   x1b   = (u16*)  take((size_t)NTOK * 1024 * 2);
  float* x1t   = (float*)take(NTOK * 4);
  u16*   hbuf  = (u16*)  take((size_t)NTOK * 4096 * 2);
  float* htv   = (float*)take(NTOK * 4);

  conv_x<<<NTOK * 1024 / 256, 256, 0, stream>>>(x, xs, xt);
  conv_w<<<(1024 * 1024) / 256, 256, 0, stream>>>(Wq, wqkv,               wqkv0,        10);
  conv_w<<<(1024 * 1024) / 256, 256, 0, stream>>>(Wk, wqkv + 1024 * 1024, wqkv0 + 1024, 10);
  conv_w<<<(1024 * 1024) / 256, 256, 0, stream>>>(Wv, wqkv + 2048 * 1024, wqkv0 + 2048, 10);
  conv_w<<<(1024 * 1024) / 256, 256, 0, stream>>>(Wo, wo_s, wo0, 10);
  conv_w<<<(4096 * 1024) / 256, 256, 0, stream>>>(W1, w1_s, w10, 10);
  conv_w<<<(1024 * 4096) / 256, 256, 0, stream>>>(W2, w2_s, w20, 12);

  gemm_bt<<<dim3(24, 32), 256, 0, stream>>>(xs, 1024, wqkv, 1024, xt, wqkv0,
      bq, bk, bv, nullptr, qkvb, 3072, 1024, 0);
  head_time<<<16384, 256, 0, stream>>>(qkvb,        qtv);
  head_time<<<16384, 256, 0, stream>>>(qkvb + 1024, ktv);
  v_transpose<<<dim3(16, 64), 256, 0, stream>>>(qkvb, vT);
  attn_kernel<<<dim3(16, 64), 256, 0, stream>>>(qkvb, qtv, ktv, vT, aoutb);
  row_time<<<NTOK / 4, 256, 0, stream>>>(aoutb, aot, 1024);
  gemm_bt<<<dim3(8, 32), 256, 0, stream>>>(aoutb, 1024, wo_s, 1024, aot, wo0,
      bo, nullptr, nullptr, zbuf, nullptr, 1024, 1024, 1);
  mid_ln<<<NTOK, 256, 0, stream>>>(zbuf, x, nullptr, nullptr, g1, be1,
      x1f, x1b, x1t, nullptr, 0, 0);
  gemm_bt<<<dim3(32, 32), 256, 0, stream>>>(x1b, 1024, w1_s, 1024, x1t, w10,
      c1, nullptr, nullptr, nullptr, hbuf, 4096, 1024, 2);
  row_time<<<NTOK / 4, 256, 0, stream>>>(hbuf, htv, 4096);
  gemm_bt<<<dim3(8, 32), 256, 0, stream>>>(hbuf, 4096, w2_s, 4096, htv, w20,
      c2, nullptr, nullptr, zbuf, nullptr, 1024, 4096, 1);
  mid_ln<<<NTOK, 256, 0, stream>>>(zbuf, nullptr, x1f, x1t, g2, be2,
      nullptr, nullptr, nullptr, out, 1, 1);
}

// Round 2
// 526.845 us; speedup vs baseline: 4.1508x; 4.1508x over previous
//
#include <hip/hip_runtime.h>

typedef unsigned short u16;
typedef unsigned int   u32;
typedef short bf16x8 __attribute__((ext_vector_type(8)));
typedef float f32x4  __attribute__((ext_vector_type(4)));

#define NTOK 4096   // B*S
#define SEQ  1024

__device__ __forceinline__ u16 f2bf(float f){
  union { float f; u32 u; } x; x.f = f;
  u32 r = (x.u + 0x7FFFu + ((x.u >> 16) & 1u)) >> 16;
  return (u16)r;
}
__device__ __forceinline__ float bf2f(u16 u){
  union { u32 u; float f; } x; x.u = ((u32)u) << 16; return x.f;
}
__device__ __forceinline__ void gl_lds16(const void* gp, void* lp){
  __builtin_amdgcn_global_load_lds(
      (const __attribute__((address_space(1))) u32*)gp,
      (__attribute__((address_space(3))) u32*)lp, 16, 0, 0);
}

// ---------------------------------------------------------------- converts
__global__ __launch_bounds__(256) void conv_x(const float* __restrict__ x,
                                              u16* __restrict__ xs, float* __restrict__ xt){
  int t = blockIdx.x * 256 + threadIdx.x;        // < NTOK*1024
  int tok = t >> 10, i = t & 1023;
  xs[t] = f2bf(x[(size_t)tok * 1025 + 1 + i]);
  if (i == 0) xt[tok] = x[(size_t)tok * 1025];
}

__global__ __launch_bounds__(256) void conv_w(const float* __restrict__ W,
                                              u16* __restrict__ Wb, float* __restrict__ w0, int shift){
  int t = blockIdx.x * 256 + threadIdx.x;        // < rows<<shift (exact grid)
  int Kin = 1 << shift;
  int r = t >> shift, i = t & (Kin - 1);
  Wb[t] = f2bf(W[(size_t)r * (Kin + 1) + 1 + i]);
  if (i == 0) w0[r] = W[(size_t)r * (Kin + 1)];
}

// ---------------------------------------------------------------- row/head times
__global__ __launch_bounds__(256) void head_time(const u16* __restrict__ src, float* __restrict__ dst){
  int g = blockIdx.x * 4 + (threadIdx.x >> 6);   // (b*16+h)*1024 + s, < 65536
  int l = threadIdx.x & 63;
  int b = g >> 14, h = (g >> 10) & 15, s = g & 1023;
  float v = bf2f(src[((size_t)(b * 1024 + s)) * 3072 + h * 64 + l]);
  float ss = v * v;
  #pragma unroll
  for (int m = 1; m < 64; m <<= 1) ss += __shfl_xor(ss, m, 64);
  if (l == 0) dst[g] = sqrtf(ss + 1.f);
}

__global__ __launch_bounds__(256) void row_time(const u16* __restrict__ src, float* __restrict__ dst, int L){
  int g = blockIdx.x * 4 + (threadIdx.x >> 6);   // token
  int l = threadIdx.x & 63;
  const u16* r = src + (size_t)g * L;
  float ss = 0.f;
  for (int j = l; j < L; j += 64){ float v = bf2f(r[j]); ss += v * v; }
  #pragma unroll
  for (int m = 1; m < 64; m <<= 1) ss += __shfl_xor(ss, m, 64);
  if (l == 0) dst[g] = sqrtf(ss + 1.f);
}

// ---------------------------------------------------------------- V transpose (+ time row)
// out: vT[(bh*65 + r)*1024 + key]; r=0 is t_v, r=1..64 are feats 0..63
__global__ __launch_bounds__(256) void v_transpose(const u16* __restrict__ qkv, u16* __restrict__ vT){
  __shared__ u16 tile[64 * 72];
  __shared__ float tvsq[64];
  const int tid = threadIdx.x;
  const int kt = blockIdx.x, bh = blockIdx.y;
  const int b = bh >> 4, h = bh & 15;
  if (tid < 64) tvsq[tid] = 0.f;
  __syncthreads();
  #pragma unroll
  for (int i = 0; i < 2; i++){
    int c = tid * 2 + i;                          // 0..511
    int key = c >> 3, fc = c & 7;
    union { uint4 v; u16 s[8]; } d;
    d.v = *(const uint4*)(qkv + ((size_t)(b * 1024 + kt * 64 + key)) * 3072 + 2048 + h * 64 + fc * 8);
    *(uint4*)&tile[key * 72 + fc * 8] = d.v;
    float ss = 0.f;
    #pragma unroll
    for (int j = 0; j < 8; j++){ float v = bf2f(d.s[j]); ss += v * v; }
    atomicAdd(&tvsq[key], ss);
  }
  __syncthreads();
  for (int c = tid; c < 520; c += 256){
    int vtr = c >> 3, kc = c & 7;
    union { uint4 v; u16 s[8]; } d;
    if (vtr == 0){
      #pragma unroll
      for (int j = 0; j < 8; j++) d.s[j] = f2bf(sqrtf(tvsq[kc * 8 + j] + 1.f));
    } else {
      int f = vtr - 1;
      #pragma unroll
      for (int j = 0; j < 8; j++) d.s[j] = tile[(kc * 8 + j) * 72 + f];
    }
    *(uint4*)(vT + ((size_t)bh * 65 + vtr) * 1024 + kt * 64 + kc * 8) = d.v;
  }
}

// ---------------------------------------------------------------- GEMM: C = A(MxK) * B(NxK)^T + at[m]*b0[n] + bias[n]
// mode 0: bf16 out, bias segmented q/k/v ; mode 1: f32 out ; mode 2: relu -> bf16 out
__global__ __launch_bounds__(256) void gemm_bt(
    const u16* __restrict__ A, int lda, const u16* __restrict__ Bm, int ldb,
    const float* __restrict__ at, const float* __restrict__ b0,
    const float* __restrict__ bias_a, const float* __restrict__ bias_b, const float* __restrict__ bias_c,
    float* __restrict__ Cf, u16* __restrict__ Cbf, int ldc, int K, int mode)
{
  __shared__ u16 As[128 * 32];
  __shared__ u16 Bs[128 * 32];
  const int tid = threadIdx.x;
  const int w = tid >> 6, l = tid & 63;
  const int l15 = l & 15, q = l >> 4;
  const int m0 = blockIdx.y * 128, n0 = blockIdx.x * 128;
  const int wr = w >> 1, wc = w & 1;
  f32x4 acc[4][4] = {};
  for (int kt = 0; kt < K; kt += 32){
    __syncthreads();
    #pragma unroll
    for (int i = 0; i < 2; i++){
      int c = (w * 2 + i) * 64 + l;               // chunk: row=c>>2, kc=c&3
      gl_lds16(A  + (size_t)(m0 + (c >> 2)) * lda + kt + (c & 3) * 8, &As[(w * 2 + i) * 512]);
      gl_lds16(Bm + (size_t)(n0 + (c >> 2)) * ldb + kt + (c & 3) * 8, &Bs[(w * 2 + i) * 512]);
    }
    __syncthreads();
    bf16x8 af[4], bfr[4];
    #pragma unroll
    for (int i = 0; i < 4; i++){
      int row = wr * 64 + i * 16 + l15;
      af[i] = *(const bf16x8*)&As[(row * 4 + q) * 8];
    }
    #pragma unroll
    for (int j = 0; j < 4; j++){
      int row = wc * 64 + j * 16 + l15;
      bfr[j] = *(const bf16x8*)&Bs[(row * 4 + q) * 8];
    }
    #pragma unroll
    for (int i = 0; i < 4; i++)
      #pragma unroll
      for (int j = 0; j < 4; j++)
        acc[i][j] = __builtin_amdgcn_mfma_f32_16x16x32_bf16(af[i], bfr[j], acc[i][j], 0, 0, 0);
  }
  #pragma unroll
  for (int i = 0; i < 4; i++){
    float atv[4];
    #pragma unroll
    for (int r = 0; r < 4; r++) atv[r] = at[m0 + wr * 64 + i * 16 + q * 4 + r];
    #pragma unroll
    for (int j = 0; j < 4; j++){
      int col = n0 + wc * 64 + j * 16 + l15;
      float b0v = b0[col];
      float bv;
      if (mode == 0) bv = (col < 1024) ? bias_a[col] : (col < 2048) ? bias_b[col - 1024] : bias_c[col - 2048];
      else bv = bias_a[col];
      #pragma unroll
      for (int r = 0; r < 4; r++){
        size_t row = (size_t)(m0 + wr * 64 + i * 16 + q * 4 + r);
        float v = acc[i][j][r] + atv[r] * b0v + bv;
        if (mode == 2) v = fmaxf(v, 0.f);
        if (mode == 1) Cf[row * ldc + col] = v;
        else           Cbf[row * ldc + col] = f2bf(v);
      }
    }
  }
}

// ---------------------------------------------------------------- flash attention
// grid (S/64, B*H); 4 waves, wave w owns 16 q-rows; online softmax (no l needed:
// lorentz normalize is scale-invariant)
__global__ __launch_bounds__(256) void attn_kernel(
    const u16* __restrict__ qkv, const float* __restrict__ qt,
    const float* __restrict__ ktm, const u16* __restrict__ vT,
    u16* __restrict__ aout)
{
  __shared__ u16 Qlds[4096];
  __shared__ u16 Klds[4096];
  __shared__ u16 Vlds[5120];   // 80 rows x 8 chunks (rows 65..79 garbage, unused cols)
  __shared__ u16 Plds[4608];   // 4 waves x 16 x 72
  const int tid = threadIdx.x;
  const int w = tid >> 6, l = tid & 63;
  const int l15 = l & 15, qd = l >> 4;
  const int q0 = blockIdx.x * 64;
  const int bh = blockIdx.y;
  const int b = bh >> 4, h = bh & 15;
  const size_t tokbase = (size_t)b << 10;

  #pragma unroll
  for (int i = 0; i < 2; i++){
    int s = (w * 2 + i) * 64 + l;
    int row = s >> 3, kc = ((s & 7) - row) & 7;   // rotation: chunk(row,kc) -> slot row*8+((kc+row)&7)
    gl_lds16(qkv + (tokbase + q0 + row) * 3072 + h * 64 + kc * 8, &Qlds[(w * 2 + i) * 512]);
  }
  __syncthreads();
  bf16x8 aq[2];
  {
    int row = w * 16 + l15;
    #pragma unroll
    for (int kk = 0; kk < 2; kk++)
      aq[kk] = *(const bf16x8*)&Qlds[(row * 8 + ((kk * 4 + qd + row) & 7)) * 8];
  }
  float tq[4];
  #pragma unroll
  for (int r = 0; r < 4; r++)
    tq[r] = qt[(size_t)bh * SEQ + q0 + w * 16 + qd * 4 + r];

  float mrow[4] = {-1e30f, -1e30f, -1e30f, -1e30f};
  f32x4 acco[5] = {};

  for (int kt = 0; kt < 16; kt++){
    __syncthreads();
    #pragma unroll
    for (int i = 0; i < 2; i++){
      int s = (w * 2 + i) * 64 + l;
      int row = s >> 3, kc = ((s & 7) - row) & 7;
      gl_lds16(qkv + (tokbase + kt * 64 + row) * 3072 + 1024 + h * 64 + kc * 8, &Klds[(w * 2 + i) * 512]);
      gl_lds16(vT + ((size_t)bh * 65 + row) * 1024 + kt * 64 + kc * 8, &Vlds[(w * 2 + i) * 512]);
    }
    if (w == 0 && l < 8){                          // vT row 64 (feat 63): slots 512..519
      gl_lds16(vT + ((size_t)bh * 65 + 64) * 1024 + kt * 64 + (l & 7) * 8, &Vlds[4096]);
    }
    __syncthreads();

    float sc[4][4];
    float mx[4] = {-1e30f, -1e30f, -1e30f, -1e30f};
    #pragma unroll
    for (int ct = 0; ct < 4; ct++){
      f32x4 z = {0.f, 0.f, 0.f, 0.f};
      int key = ct * 16 + l15;
      #pragma unroll
      for (int kk = 0; kk < 2; kk++){
        bf16x8 bk = *(const bf16x8*)&Klds[(key * 8 + ((kk * 4 + qd + key) & 7)) * 8];
        z = __builtin_amdgcn_mfma_f32_16x16x32_bf16(aq[kk], bk, z, 0, 0, 0);
      }
      float tk = ktm[(size_t)bh * SEQ + kt * 64 + key];
      #pragma unroll
      for (int r = 0; r < 4; r++){
        float s = 0.25f + 0.25f * (z[r] - tq[r] * tk);
        sc[ct][r] = s;
        mx[r] = fmaxf(mx[r], s);
      }
    }
    #pragma unroll
    for (int r = 0; r < 4; r++){
      #pragma unroll
      for (int msk = 1; msk < 16; msk <<= 1)
        mx[r] = fmaxf(mx[r], __shfl_xor(mx[r], msk, 64));
      float mnew = fmaxf(mrow[r], mx[r]);
      float alpha = __expf(mrow[r] - mnew);
      mrow[r] = mnew;
      #pragma unroll
      for (int co = 0; co < 5; co++) acco[co][r] *= alpha;
      mx[r] = mnew;
    }
    #pragma unroll
    for (int ct = 0; ct < 4; ct++)
      #pragma unroll
      for (int r = 0; r < 4; r++)
        Plds[w * 1152 + (qd * 4 + r) * 72 + ct * 16 + l15] = f2bf(__expf(sc[ct][r] - mx[r]));
    asm volatile("s_waitcnt lgkmcnt(0)" ::: "memory");
    bf16x8 ap[2];
    #pragma unroll
    for (int kk = 0; kk < 2; kk++)
      ap[kk] = *(const bf16x8*)&Plds[w * 1152 + l15 * 72 + kk * 32 + qd * 8];
    #pragma unroll
    for (int co = 0; co < 5; co++){
      int vtr = co * 16 + l15;
      #pragma unroll
      for (int kk = 0; kk < 2; kk++){
        bf16x8 bv = *(const bf16x8*)&Vlds[(vtr * 8 + ((kk * 4 + qd + vtr) & 7)) * 8];
        acco[co] = __builtin_amdgcn_mfma_f32_16x16x32_bf16(ap[kk], bv, acco[co], 0, 0, 0);
      }
    }
  }
  #pragma unroll
  for (int r = 0; r < 4; r++){
    float ss = 0.f;
    #pragma unroll
    for (int co = 0; co < 5; co++){
      int col = co * 16 + l15;
      float v = acco[co][r];
      if (col == 0) ss -= v * v;
      else if (col < 65) ss += v * v;
    }
    #pragma unroll
    for (int msk = 1; msk < 16; msk <<= 1) ss += __shfl_xor(ss, msk, 64);
    float rn = rsqrtf(fmaxf(fabsf(ss), 1e-8f));
    size_t rowg = tokbase + q0 + w * 16 + qd * 4 + r;
    #pragma unroll
    for (int co = 0; co < 5; co++){
      int col = co * 16 + l15;
      if (col >= 1 && col < 65)
        aout[rowg * 1024 + h * 64 + col - 1] = f2bf(acco[co][r] * rn);
    }
  }
}

// ---------------------------------------------------------------- midpoint + hyp_layernorm
__device__ __forceinline__ float block_sum(float v, float* red){
  int tid = threadIdx.x;
  #pragma unroll
  for (int m = 1; m < 64; m <<= 1) v += __shfl_xor(v, m, 64);
  __syncthreads();
  if ((tid & 63) == 0) red[tid >> 6] = v;
  __syncthreads();
  return red[0] + red[1] + red[2] + red[3];
}

__global__ __launch_bounds__(256) void mid_ln(
    const float* __restrict__ z, const float* __restrict__ xfull,
    const float* __restrict__ xs, const float* __restrict__ xtv,
    const float* __restrict__ gam, const float* __restrict__ bet,
    float* __restrict__ of, u16* __restrict__ ob, float* __restrict__ ot,
    float* __restrict__ ofull, int mode_x, int mode_out)
{
  __shared__ float red[4];
  const int tid = threadIdx.x;
  const int tok = blockIdx.x;
  const float* zr = z + (size_t)tok * 1024;
  float zv[4], xv[4], xtime;
  if (mode_x == 0){
    const float* xr = xfull + (size_t)tok * 1025;
    xtime = xr[0];
    #pragma unroll
    for (int j = 0; j < 4; j++) xv[j] = xr[1 + tid + j * 256];
  } else {
    xtime = xtv[tok];
    const float* xr = xs + (size_t)tok * 1024;
    #pragma unroll
    for (int j = 0; j < 4; j++) xv[j] = xr[tid + j * 256];
  }
  float ssz = 0.f;
  #pragma unroll
  for (int j = 0; j < 4; j++){ zv[j] = zr[tid + j * 256]; ssz += zv[j] * zv[j]; }
  ssz = block_sum(ssz, red);
  float tz = sqrtf(ssz + 1.f);
  float av[4]; float ssa = 0.f;
  #pragma unroll
  for (int j = 0; j < 4; j++){ av[j] = 0.5f * (zv[j] + xv[j]); ssa += av[j] * av[j]; }
  ssa = block_sum(ssa, red);
  float avt = 0.5f * (tz + xtime);
  float rn = rsqrtf(fmaxf(fabsf(ssa - avt * avt), 1e-8f));
  float uv[4]; float su = 0.f, squ = 0.f;
  #pragma unroll
  for (int j = 0; j < 4; j++){ uv[j] = av[j] * rn; su += uv[j]; squ += uv[j] * uv[j]; }
  su = block_sum(su, red);
  squ = block_sum(squ, red);
  float mu = su * (1.f / 1024.f);
  float var = squ * (1.f / 1024.f) - mu * mu;
  float rv = rsqrtf(fmaxf(var, 0.f) + 1e-5f);
  float sv[4]; float sss = 0.f;
  #pragma unroll
  for (int j = 0; j < 4; j++){
    int i = tid + j * 256;
    sv[j] = (uv[j] - mu) * rv * gam[i] + bet[i];
    sss += sv[j] * sv[j];
  }
  sss = block_sum(sss, red);
  float tout = sqrtf(sss + 1.f);
  if (mode_out == 0){
    #pragma unroll
    for (int j = 0; j < 4; j++){
      int i = tid + j * 256;
      of[(size_t)tok * 1024 + i] = sv[j];
      ob[(size_t)tok * 1024 + i] = f2bf(sv[j]);
    }
    if (tid == 0) ot[tok] = tout;
  } else {
    float* orow = ofull + (size_t)tok * 1025;
    #pragma unroll
    for (int j = 0; j < 4; j++) orow[1 + tid + j * 256] = sv[j];
    if (tid == 0) orow[0] = tout;
  }
}

// ---------------------------------------------------------------- launch
extern "C" void kernel_launch(void* const* d_in, const int* in_sizes, int n_in,
                              void* d_out, int out_size, void* d_ws, size_t ws_size,
                              hipStream_t stream){
  const float* x   = (const float*)d_in[0];
  const float* Wq  = (const float*)d_in[1];
  const float* bq  = (const float*)d_in[2];
  const float* Wk  = (const float*)d_in[3];
  const float* bk  = (const float*)d_in[4];
  const float* Wv  = (const float*)d_in[5];
  const float* bv  = (const float*)d_in[6];
  const float* Wo  = (const float*)d_in[7];
  const float* bo  = (const float*)d_in[8];
  const float* g1  = (const float*)d_in[9];
  const float* be1 = (const float*)d_in[10];
  const float* W1  = (const float*)d_in[11];
  const float* c1  = (const float*)d_in[12];
  const float* W2  = (const float*)d_in[13];
  const float* c2  = (const float*)d_in[14];
  const float* g2  = (const float*)d_in[15];
  const float* be2 = (const float*)d_in[16];
  float* out = (float*)d_out;

  char* p = (char*)d_ws;
  auto take = [&](size_t n){ char* r = p; p += (n + 255) & ~(size_t)255; return r; };
  u16*   xs    = (u16*)  take((size_t)NTOK * 1024 * 2);
  float* xt    = (float*)take(NTOK * 4);
  u16*   wqkv  = (u16*)  take((size_t)3072 * 1024 * 2);
  float* wqkv0 = (float*)take(3072 * 4);
  u16*   wo_s  = (u16*)  take((size_t)1024 * 1024 * 2);
  float* wo0   = (float*)take(1024 * 4);
  u16*   w1_s  = (u16*)  take((size_t)4096 * 1024 * 2);
  float* w10   = (float*)take(4096 * 4);
  u16*   w2_s  = (u16*)  take((size_t)1024 * 4096 * 2);
  float* w20   = (float*)take(1024 * 4);
  u16*   qkvb  = (u16*)  take((size_t)NTOK * 3072 * 2);
  float* qtv   = (float*)take((size_t)64 * 1024 * 4);
  float* ktv   = (float*)take((size_t)64 * 1024 * 4);
  u16*   vT    = (u16*)  take((size_t)64 * 65 * 1024 * 2);
  u16*   aoutb = (u16*)  take((size_t)NTOK * 1024 * 2);
  float* aot   = (float*)take(NTOK * 4);
  float* zbuf  = (float*)take((size_t)NTOK * 1024 * 4);
  float* x1f   = (float*)take((size_t)NTOK * 1024 * 4);
  u16*   x1b   = (u16*)  take((size_t)NTOK * 1024 * 2);
  float* x1t   = (float*)take(NTOK * 4);
  u16*   hbuf  = (u16*)  take((size_t)NTOK * 4096 * 2);
  float* htv   = (float*)take(NTOK * 4);

  conv_x<<<NTOK * 1024 / 256, 256, 0, stream>>>(x, xs, xt);
  conv_w<<<(1024 * 1024) / 256, 256, 0, stream>>>(Wq, wqkv,               wqkv0,        10);
  conv_w<<<(1024 * 1024) / 256, 256, 0, stream>>>(Wk, wqkv + 1024 * 1024, wqkv0 + 1024, 10);
  conv_w<<<(1024 * 1024) / 256, 256, 0, stream>>>(Wv, wqkv + 2048 * 1024, wqkv0 + 2048, 10);
  conv_w<<<(1024 * 1024) / 256, 256, 0, stream>>>(Wo, wo_s, wo0, 10);
  conv_w<<<(4096 * 1024) / 256, 256, 0, stream>>>(W1, w1_s, w10, 10);
  conv_w<<<(1024 * 4096) / 256, 256, 0, stream>>>(W2, w2_s, w20, 12);

  gemm_bt<<<dim3(24, 32), 256, 0, stream>>>(xs, 1024, wqkv, 1024, xt, wqkv0,
      bq, bk, bv, nullptr, qkvb, 3072, 1024, 0);
  head_time<<<16384, 256, 0, stream>>>(qkvb,        qtv);
  head_time<<<16384, 256, 0, stream>>>(qkvb + 1024, ktv);
  v_transpose<<<dim3(16, 64), 256, 0, stream>>>(qkvb, vT);
  attn_kernel<<<dim3(16, 64), 256, 0, stream>>>(qkvb, qtv, ktv, vT, aoutb);
  row_time<<<NTOK / 4, 256, 0, stream>>>(aoutb, aot, 1024);
  gemm_bt<<<dim3(8, 32), 256, 0, stream>>>(aoutb, 1024, wo_s, 1024, aot, wo0,
      bo, nullptr, nullptr, zbuf, nullptr, 1024, 1024, 1);
  mid_ln<<<NTOK, 256, 0, stream>>>(zbuf, x, nullptr, nullptr, g1, be1,
      x1f, x1b, x1t, nullptr, 0, 0);
  gemm_bt<<<dim3(32, 32), 256, 0, stream>>>(x1b, 1024, w1_s, 1024, x1t, w10,
      c1, nullptr, nullptr, nullptr, hbuf, 4096, 1024, 2);
  row_time<<<NTOK / 4, 256, 0, stream>>>(hbuf, htv, 4096);
  gemm_bt<<<dim3(8, 32), 256, 0, stream>>>(hbuf, 4096, w2_s, 4096, htv, w20,
      c2, nullptr, nullptr, zbuf, nullptr, 1024, 4096, 1);
  mid_ln<<<NTOK, 256, 0, stream>>>(zbuf, nullptr, x1f, x1t, g2, be2,
      nullptr, nullptr, nullptr, out, 1, 1);
}

// Round 3
// 514.504 us; speedup vs baseline: 4.2503x; 1.0240x over previous
//
#include <hip/hip_runtime.h>

typedef unsigned short u16;
typedef unsigned int   u32;
typedef short bf16x8 __attribute__((ext_vector_type(8)));
typedef float f32x4  __attribute__((ext_vector_type(4)));

#define NTOK 4096   // B*S
#define SEQ  1024

__device__ __forceinline__ u16 f2bf(float f){
  union { float f; u32 u; } x; x.f = f;
  u32 r = (x.u + 0x7FFFu + ((x.u >> 16) & 1u)) >> 16;
  return (u16)r;
}
__device__ __forceinline__ float bf2f(u16 u){
  union { u32 u; float f; } x; x.u = ((u32)u) << 16; return x.f;
}
__device__ __forceinline__ void gl_lds16(const void* gp, void* lp){
  __builtin_amdgcn_global_load_lds(
      (const __attribute__((address_space(1))) u32*)gp,
      (__attribute__((address_space(3))) u32*)lp, 16, 0, 0);
}

// ---------------------------------------------------------------- converts
__global__ __launch_bounds__(256) void conv_x(const float* __restrict__ x,
                                              u16* __restrict__ xs, float* __restrict__ xt){
  int t = blockIdx.x * 256 + threadIdx.x;        // < NTOK*1024
  int tok = t >> 10, i = t & 1023;
  xs[t] = f2bf(x[(size_t)tok * 1025 + 1 + i]);
  if (i == 0) xt[tok] = x[(size_t)tok * 1025];
}

__global__ __launch_bounds__(256) void conv_w(const float* __restrict__ W,
                                              u16* __restrict__ Wb, float* __restrict__ w0, int shift){
  int t = blockIdx.x * 256 + threadIdx.x;        // < rows<<shift (exact grid)
  int Kin = 1 << shift;
  int r = t >> shift, i = t & (Kin - 1);
  Wb[t] = f2bf(W[(size_t)r * (Kin + 1) + 1 + i]);
  if (i == 0) w0[r] = W[(size_t)r * (Kin + 1)];
}

// ---------------------------------------------------------------- row/head times
__global__ __launch_bounds__(256) void head_time(const u16* __restrict__ src, float* __restrict__ dst){
  int g = blockIdx.x * 4 + (threadIdx.x >> 6);   // (b*16+h)*1024 + s, < 65536
  int l = threadIdx.x & 63;
  int b = g >> 14, h = (g >> 10) & 15, s = g & 1023;
  float v = bf2f(src[((size_t)(b * 1024 + s)) * 3072 + h * 64 + l]);
  float ss = v * v;
  #pragma unroll
  for (int m = 1; m < 64; m <<= 1) ss += __shfl_xor(ss, m, 64);
  if (l == 0) dst[g] = sqrtf(ss + 1.f);
}

__global__ __launch_bounds__(256) void row_time(const u16* __restrict__ src, float* __restrict__ dst, int L){
  int g = blockIdx.x * 4 + (threadIdx.x >> 6);   // token
  int l = threadIdx.x & 63;
  const u16* r = src + (size_t)g * L;
  float ss = 0.f;
  for (int j = l; j < L; j += 64){ float v = bf2f(r[j]); ss += v * v; }
  #pragma unroll
  for (int m = 1; m < 64; m <<= 1) ss += __shfl_xor(ss, m, 64);
  if (l == 0) dst[g] = sqrtf(ss + 1.f);
}

// ---------------------------------------------------------------- V transpose (+ time row)
// out: vT[(bh*65 + r)*1024 + key]; r=0 is t_v, r=1..64 are feats 0..63
__global__ __launch_bounds__(256) void v_transpose(const u16* __restrict__ qkv, u16* __restrict__ vT){
  __shared__ u16 tile[64 * 72];
  __shared__ float tvsq[64];
  const int tid = threadIdx.x;
  const int kt = blockIdx.x, bh = blockIdx.y;
  const int b = bh >> 4, h = bh & 15;
  if (tid < 64) tvsq[tid] = 0.f;
  __syncthreads();
  #pragma unroll
  for (int i = 0; i < 2; i++){
    int c = tid * 2 + i;                          // 0..511
    int key = c >> 3, fc = c & 7;
    union { uint4 v; u16 s[8]; } d;
    d.v = *(const uint4*)(qkv + ((size_t)(b * 1024 + kt * 64 + key)) * 3072 + 2048 + h * 64 + fc * 8);
    *(uint4*)&tile[key * 72 + fc * 8] = d.v;
    float ss = 0.f;
    #pragma unroll
    for (int j = 0; j < 8; j++){ float v = bf2f(d.s[j]); ss += v * v; }
    atomicAdd(&tvsq[key], ss);
  }
  __syncthreads();
  for (int c = tid; c < 520; c += 256){
    int vtr = c >> 3, kc = c & 7;
    union { uint4 v; u16 s[8]; } d;
    if (vtr == 0){
      #pragma unroll
      for (int j = 0; j < 8; j++) d.s[j] = f2bf(sqrtf(tvsq[kc * 8 + j] + 1.f));
    } else {
      int f = vtr - 1;
      #pragma unroll
      for (int j = 0; j < 8; j++) d.s[j] = tile[(kc * 8 + j) * 72 + f];
    }
    *(uint4*)(vT + ((size_t)bh * 65 + vtr) * 1024 + kt * 64 + kc * 8) = d.v;
  }
}

// ---------------------------------------------------------------- GEMM: C = A(MxK) * B(NxK)^T + at[m]*b0[n] + bias[n]
// mode 0: bf16 out, bias segmented q/k/v ; mode 1: f32 out ; mode 2: relu -> bf16 out
// Split-K: blockIdx.z = K-slice (Kslice = per-slice length); slice s writes
// Cf + s*Mtot*ldc (mode 1 only); bias/time-term added by slice 0 only.
__global__ __launch_bounds__(256) void gemm_bt(
    const u16* __restrict__ A, int lda, const u16* __restrict__ Bm, int ldb,
    const float* __restrict__ at, const float* __restrict__ b0,
    const float* __restrict__ bias_a, const float* __restrict__ bias_b, const float* __restrict__ bias_c,
    float* __restrict__ Cf, u16* __restrict__ Cbf, int ldc, int Kslice, int mode)
{
  __shared__ u16 As[128 * 32];
  __shared__ u16 Bs[128 * 32];
  const int tid = threadIdx.x;
  const int w = tid >> 6, l = tid & 63;
  const int l15 = l & 15, q = l >> 4;
  const int m0 = blockIdx.y * 128, n0 = blockIdx.x * 128;
  const int ks = blockIdx.z;
  const int kbeg = ks * Kslice;
  const int wr = w >> 1, wc = w & 1;
  f32x4 acc[4][4] = {};
  for (int kt = kbeg; kt < kbeg + Kslice; kt += 32){
    __syncthreads();
    #pragma unroll
    for (int i = 0; i < 2; i++){
      int c = (w * 2 + i) * 64 + l;               // chunk: row=c>>2, kc=c&3
      gl_lds16(A  + (size_t)(m0 + (c >> 2)) * lda + kt + (c & 3) * 8, &As[(w * 2 + i) * 512]);
      gl_lds16(Bm + (size_t)(n0 + (c >> 2)) * ldb + kt + (c & 3) * 8, &Bs[(w * 2 + i) * 512]);
    }
    __syncthreads();
    bf16x8 af[4], bfr[4];
    #pragma unroll
    for (int i = 0; i < 4; i++){
      int row = wr * 64 + i * 16 + l15;
      af[i] = *(const bf16x8*)&As[(row * 4 + q) * 8];
    }
    #pragma unroll
    for (int j = 0; j < 4; j++){
      int row = wc * 64 + j * 16 + l15;
      bfr[j] = *(const bf16x8*)&Bs[(row * 4 + q) * 8];
    }
    #pragma unroll
    for (int i = 0; i < 4; i++)
      #pragma unroll
      for (int j = 0; j < 4; j++)
        acc[i][j] = __builtin_amdgcn_mfma_f32_16x16x32_bf16(af[i], bfr[j], acc[i][j], 0, 0, 0);
  }
  const size_t slice_off = (size_t)ks * (size_t)(gridDim.y * 128) * ldc;
  #pragma unroll
  for (int i = 0; i < 4; i++){
    float atv[4];
    #pragma unroll
    for (int r = 0; r < 4; r++) atv[r] = at[m0 + wr * 64 + i * 16 + q * 4 + r];
    #pragma unroll
    for (int j = 0; j < 4; j++){
      int col = n0 + wc * 64 + j * 16 + l15;
      float b0v = b0[col];
      float bv;
      if (mode == 0) bv = (col < 1024) ? bias_a[col] : (col < 2048) ? bias_b[col - 1024] : bias_c[col - 2048];
      else bv = bias_a[col];
      #pragma unroll
      for (int r = 0; r < 4; r++){
        size_t row = (size_t)(m0 + wr * 64 + i * 16 + q * 4 + r);
        float add = (ks == 0) ? (atv[r] * b0v + bv) : 0.f;
        float v = acc[i][j][r] + add;
        if (mode == 2) v = fmaxf(v, 0.f);
        if (mode == 1) Cf[slice_off + row * ldc + col] = v;
        else           Cbf[row * ldc + col] = f2bf(v);
      }
    }
  }
}

// ---------------------------------------------------------------- flash attention
// grid (S/64, B*H); 4 waves, wave w owns 16 q-rows; online softmax (no l needed:
// lorentz normalize is scale-invariant)
__global__ __launch_bounds__(256) void attn_kernel(
    const u16* __restrict__ qkv, const float* __restrict__ qt,
    const float* __restrict__ ktm, const u16* __restrict__ vT,
    u16* __restrict__ aout)
{
  __shared__ u16 Qlds[4096];
  __shared__ u16 Klds[4096];
  __shared__ u16 Vlds[5120];   // 80 rows x 8 chunks (rows 65..79 garbage, unused cols)
  __shared__ u16 Plds[4608];   // 4 waves x 16 x 72
  const int tid = threadIdx.x;
  const int w = tid >> 6, l = tid & 63;
  const int l15 = l & 15, qd = l >> 4;
  const int q0 = blockIdx.x * 64;
  const int bh = blockIdx.y;
  const int b = bh >> 4, h = bh & 15;
  const size_t tokbase = (size_t)b << 10;

  #pragma unroll
  for (int i = 0; i < 2; i++){
    int s = (w * 2 + i) * 64 + l;
    int row = s >> 3, kc = ((s & 7) - row) & 7;   // rotation: chunk(row,kc) -> slot row*8+((kc+row)&7)
    gl_lds16(qkv + (tokbase + q0 + row) * 3072 + h * 64 + kc * 8, &Qlds[(w * 2 + i) * 512]);
  }
  __syncthreads();
  bf16x8 aq[2];
  {
    int row = w * 16 + l15;
    #pragma unroll
    for (int kk = 0; kk < 2; kk++)
      aq[kk] = *(const bf16x8*)&Qlds[(row * 8 + ((kk * 4 + qd + row) & 7)) * 8];
  }
  float tq[4];
  #pragma unroll
  for (int r = 0; r < 4; r++)
    tq[r] = qt[(size_t)bh * SEQ + q0 + w * 16 + qd * 4 + r];

  float mrow[4] = {-1e30f, -1e30f, -1e30f, -1e30f};
  f32x4 acco[5] = {};

  for (int kt = 0; kt < 16; kt++){
    __syncthreads();
    #pragma unroll
    for (int i = 0; i < 2; i++){
      int s = (w * 2 + i) * 64 + l;
      int row = s >> 3, kc = ((s & 7) - row) & 7;
      gl_lds16(qkv + (tokbase + kt * 64 + row) * 3072 + 1024 + h * 64 + kc * 8, &Klds[(w * 2 + i) * 512]);
      gl_lds16(vT + ((size_t)bh * 65 + row) * 1024 + kt * 64 + kc * 8, &Vlds[(w * 2 + i) * 512]);
    }
    if (w == 0 && l < 8){                          // vT row 64 (feat 63): slots 512..519
      gl_lds16(vT + ((size_t)bh * 65 + 64) * 1024 + kt * 64 + (l & 7) * 8, &Vlds[4096]);
    }
    __syncthreads();

    float sc[4][4];
    float mx[4] = {-1e30f, -1e30f, -1e30f, -1e30f};
    #pragma unroll
    for (int ct = 0; ct < 4; ct++){
      f32x4 z = {0.f, 0.f, 0.f, 0.f};
      int key = ct * 16 + l15;
      #pragma unroll
      for (int kk = 0; kk < 2; kk++){
        bf16x8 bk = *(const bf16x8*)&Klds[(key * 8 + ((kk * 4 + qd + key) & 7)) * 8];
        z = __builtin_amdgcn_mfma_f32_16x16x32_bf16(aq[kk], bk, z, 0, 0, 0);
      }
      float tk = ktm[(size_t)bh * SEQ + kt * 64 + key];
      #pragma unroll
      for (int r = 0; r < 4; r++){
        float s = 0.25f + 0.25f * (z[r] - tq[r] * tk);
        sc[ct][r] = s;
        mx[r] = fmaxf(mx[r], s);
      }
    }
    #pragma unroll
    for (int r = 0; r < 4; r++){
      #pragma unroll
      for (int msk = 1; msk < 16; msk <<= 1)
        mx[r] = fmaxf(mx[r], __shfl_xor(mx[r], msk, 64));
      float mnew = fmaxf(mrow[r], mx[r]);
      float alpha = __expf(mrow[r] - mnew);
      mrow[r] = mnew;
      #pragma unroll
      for (int co = 0; co < 5; co++) acco[co][r] *= alpha;
      mx[r] = mnew;
    }
    #pragma unroll
    for (int ct = 0; ct < 4; ct++)
      #pragma unroll
      for (int r = 0; r < 4; r++)
        Plds[w * 1152 + (qd * 4 + r) * 72 + ct * 16 + l15] = f2bf(__expf(sc[ct][r] - mx[r]));
    asm volatile("s_waitcnt lgkmcnt(0)" ::: "memory");
    bf16x8 ap[2];
    #pragma unroll
    for (int kk = 0; kk < 2; kk++)
      ap[kk] = *(const bf16x8*)&Plds[w * 1152 + l15 * 72 + kk * 32 + qd * 8];
    #pragma unroll
    for (int co = 0; co < 5; co++){
      int vtr = co * 16 + l15;
      #pragma unroll
      for (int kk = 0; kk < 2; kk++){
        bf16x8 bv = *(const bf16x8*)&Vlds[(vtr * 8 + ((kk * 4 + qd + vtr) & 7)) * 8];
        acco[co] = __builtin_amdgcn_mfma_f32_16x16x32_bf16(ap[kk], bv, acco[co], 0, 0, 0);
      }
    }
  }
  #pragma unroll
  for (int r = 0; r < 4; r++){
    float ss = 0.f;
    #pragma unroll
    for (int co = 0; co < 5; co++){
      int col = co * 16 + l15;
      float v = acco[co][r];
      if (col == 0) ss -= v * v;
      else if (col < 65) ss += v * v;
    }
    #pragma unroll
    for (int msk = 1; msk < 16; msk <<= 1) ss += __shfl_xor(ss, msk, 64);
    float rn = rsqrtf(fmaxf(fabsf(ss), 1e-8f));
    size_t rowg = tokbase + q0 + w * 16 + qd * 4 + r;
    #pragma unroll
    for (int co = 0; co < 5; co++){
      int col = co * 16 + l15;
      if (col >= 1 && col < 65)
        aout[rowg * 1024 + h * 64 + col - 1] = f2bf(acco[co][r] * rn);
    }
  }
}

// ---------------------------------------------------------------- midpoint + hyp_layernorm
__device__ __forceinline__ float block_sum(float v, float* red){
  int tid = threadIdx.x;
  #pragma unroll
  for (int m = 1; m < 64; m <<= 1) v += __shfl_xor(v, m, 64);
  __syncthreads();
  if ((tid & 63) == 0) red[tid >> 6] = v;
  __syncthreads();
  return red[0] + red[1] + red[2] + red[3];
}

__global__ __launch_bounds__(256) void mid_ln(
    const float* __restrict__ z, const float* __restrict__ xfull,
    const float* __restrict__ xs, const float* __restrict__ xtv,
    const float* __restrict__ gam, const float* __restrict__ bet,
    float* __restrict__ of, u16* __restrict__ ob, float* __restrict__ ot,
    float* __restrict__ ofull, int mode_x, int mode_out, int nsl)
{
  __shared__ float red[4];
  const int tid = threadIdx.x;
  const int tok = blockIdx.x;
  float zv[4], xv[4], xtime;
  if (mode_x == 0){
    const float* xr = xfull + (size_t)tok * 1025;
    xtime = xr[0];
    #pragma unroll
    for (int j = 0; j < 4; j++) xv[j] = xr[1 + tid + j * 256];
  } else {
    xtime = xtv[tok];
    const float* xr = xs + (size_t)tok * 1024;
    #pragma unroll
    for (int j = 0; j < 4; j++) xv[j] = xr[tid + j * 256];
  }
  // sum split-K slices of z
  {
    const float* zr = z + (size_t)tok * 1024;
    #pragma unroll
    for (int j = 0; j < 4; j++) zv[j] = zr[tid + j * 256];
    for (int s = 1; s < nsl; s++){
      const float* zs = z + (size_t)s * NTOK * 1024 + (size_t)tok * 1024;
      #pragma unroll
      for (int j = 0; j < 4; j++) zv[j] += zs[tid + j * 256];
    }
  }
  float ssz = 0.f;
  #pragma unroll
  for (int j = 0; j < 4; j++) ssz += zv[j] * zv[j];
  ssz = block_sum(ssz, red);
  float tz = sqrtf(ssz + 1.f);
  float av[4]; float ssa = 0.f;
  #pragma unroll
  for (int j = 0; j < 4; j++){ av[j] = 0.5f * (zv[j] + xv[j]); ssa += av[j] * av[j]; }
  ssa = block_sum(ssa, red);
  float avt = 0.5f * (tz + xtime);
  float rn = rsqrtf(fmaxf(fabsf(ssa - avt * avt), 1e-8f));
  float uv[4]; float su = 0.f, squ = 0.f;
  #pragma unroll
  for (int j = 0; j < 4; j++){ uv[j] = av[j] * rn; su += uv[j]; squ += uv[j] * uv[j]; }
  su = block_sum(su, red);
  squ = block_sum(squ, red);
  float mu = su * (1.f / 1024.f);
  float var = squ * (1.f / 1024.f) - mu * mu;
  float rv = rsqrtf(fmaxf(var, 0.f) + 1e-5f);
  float sv[4]; float sss = 0.f;
  #pragma unroll
  for (int j = 0; j < 4; j++){
    int i = tid + j * 256;
    sv[j] = (uv[j] - mu) * rv * gam[i] + bet[i];
    sss += sv[j] * sv[j];
  }
  sss = block_sum(sss, red);
  float tout = sqrtf(sss + 1.f);
  if (mode_out == 0){
    #pragma unroll
    for (int j = 0; j < 4; j++){
      int i = tid + j * 256;
      of[(size_t)tok * 1024 + i] = sv[j];
      ob[(size_t)tok * 1024 + i] = f2bf(sv[j]);
    }
    if (tid == 0) ot[tok] = tout;
  } else {
    float* orow = ofull + (size_t)tok * 1025;
    #pragma unroll
    for (int j = 0; j < 4; j++) orow[1 + tid + j * 256] = sv[j];
    if (tid == 0) orow[0] = tout;
  }
}

// ---------------------------------------------------------------- launch
extern "C" void kernel_launch(void* const* d_in, const int* in_sizes, int n_in,
                              void* d_out, int out_size, void* d_ws, size_t ws_size,
                              hipStream_t stream){
  const float* x   = (const float*)d_in[0];
  const float* Wq  = (const float*)d_in[1];
  const float* bq  = (const float*)d_in[2];
  const float* Wk  = (const float*)d_in[3];
  const float* bk  = (const float*)d_in[4];
  const float* Wv  = (const float*)d_in[5];
  const float* bv  = (const float*)d_in[6];
  const float* Wo  = (const float*)d_in[7];
  const float* bo  = (const float*)d_in[8];
  const float* g1  = (const float*)d_in[9];
  const float* be1 = (const float*)d_in[10];
  const float* W1  = (const float*)d_in[11];
  const float* c1  = (const float*)d_in[12];
  const float* W2  = (const float*)d_in[13];
  const float* c2  = (const float*)d_in[14];
  const float* g2  = (const float*)d_in[15];
  const float* be2 = (const float*)d_in[16];
  float* out = (float*)d_out;

  char* p = (char*)d_ws;
  auto take = [&](size_t n){ char* r = p; p += (n + 255) & ~(size_t)255; return r; };
  u16*   xs    = (u16*)  take((size_t)NTOK * 1024 * 2);
  float* xt    = (float*)take(NTOK * 4);
  u16*   wqkv  = (u16*)  take((size_t)3072 * 1024 * 2);
  float* wqkv0 = (float*)take(3072 * 4);
  u16*   wo_s  = (u16*)  take((size_t)1024 * 1024 * 2);
  float* wo0   = (float*)take(1024 * 4);
  u16*   w1_s  = (u16*)  take((size_t)4096 * 1024 * 2);
  float* w10   = (float*)take(4096 * 4);
  u16*   w2_s  = (u16*)  take((size_t)1024 * 4096 * 2);
  float* w20   = (float*)take(1024 * 4);
  u16*   qkvb  = (u16*)  take((size_t)NTOK * 3072 * 2);
  float* qtv   = (float*)take((size_t)64 * 1024 * 4);
  float* ktv   = (float*)take((size_t)64 * 1024 * 4);
  u16*   vT    = (u16*)  take((size_t)64 * 65 * 1024 * 2);
  u16*   aoutb = (u16*)  take((size_t)NTOK * 1024 * 2);
  float* aot   = (float*)take(NTOK * 4);
  float* zbuf  = (float*)take((size_t)4 * NTOK * 1024 * 4);   // 4 split-K slices
  float* x1f   = (float*)take((size_t)NTOK * 1024 * 4);
  u16*   x1b   = (u16*)  take((size_t)NTOK * 1024 * 2);
  float* x1t   = (float*)take(NTOK * 4);
  u16*   hbuf  = (u16*)  take((size_t)NTOK * 4096 * 2);
  float* htv   = (float*)take(NTOK * 4);

  conv_x<<<NTOK * 1024 / 256, 256, 0, stream>>>(x, xs, xt);
  conv_w<<<(1024 * 1024) / 256, 256, 0, stream>>>(Wq, wqkv,               wqkv0,        10);
  conv_w<<<(1024 * 1024) / 256, 256, 0, stream>>>(Wk, wqkv + 1024 * 1024, wqkv0 + 1024, 10);
  conv_w<<<(1024 * 1024) / 256, 256, 0, stream>>>(Wv, wqkv + 2048 * 1024, wqkv0 + 2048, 10);
  conv_w<<<(1024 * 1024) / 256, 256, 0, stream>>>(Wo, wo_s, wo0, 10);
  conv_w<<<(4096 * 1024) / 256, 256, 0, stream>>>(W1, w1_s, w10, 10);
  conv_w<<<(1024 * 4096) / 256, 256, 0, stream>>>(W2, w2_s, w20, 12);

  gemm_bt<<<dim3(24, 32), 256, 0, stream>>>(xs, 1024, wqkv, 1024, xt, wqkv0,
      bq, bk, bv, nullptr, qkvb, 3072, 1024, 0);
  head_time<<<16384, 256, 0, stream>>>(qkvb,        qtv);
  head_time<<<16384, 256, 0, stream>>>(qkvb + 1024, ktv);
  v_transpose<<<dim3(16, 64), 256, 0, stream>>>(qkvb, vT);
  attn_kernel<<<dim3(16, 64), 256, 0, stream>>>(qkvb, qtv, ktv, vT, aoutb);
  row_time<<<NTOK / 4, 256, 0, stream>>>(aoutb, aot, 1024);
  // O-proj: split-K x2 -> 512 blocks (2/CU)
  gemm_bt<<<dim3(8, 32, 2), 256, 0, stream>>>(aoutb, 1024, wo_s, 1024, aot, wo0,
      bo, nullptr, nullptr, zbuf, nullptr, 1024, 512, 1);
  mid_ln<<<NTOK, 256, 0, stream>>>(zbuf, x, nullptr, nullptr, g1, be1,
      x1f, x1b, x1t, nullptr, 0, 0, 2);
  gemm_bt<<<dim3(32, 32), 256, 0, stream>>>(x1b, 1024, w1_s, 1024, x1t, w10,
      c1, nullptr, nullptr, nullptr, hbuf, 4096, 1024, 2);
  row_time<<<NTOK / 4, 256, 0, stream>>>(hbuf, htv, 4096);
  // MLP2: split-K x4 -> 1024 blocks (3/CU by VGPR)
  gemm_bt<<<dim3(8, 32, 4), 256, 0, stream>>>(hbuf, 4096, w2_s, 4096, htv, w20,
      c2, nullptr, nullptr, zbuf, nullptr, 1024, 1024, 1);
  mid_ln<<<NTOK, 256, 0, stream>>>(zbuf, nullptr, x1f, x1t, g2, be2,
      nullptr, nullptr, nullptr, out, 1, 1, 4);
}

// Round 4
// 484.096 us; speedup vs baseline: 4.5173x; 1.0628x over previous
//
#include <hip/hip_runtime.h>

typedef unsigned short u16;
typedef unsigned int   u32;
typedef short bf16x8 __attribute__((ext_vector_type(8)));
typedef float f32x4  __attribute__((ext_vector_type(4)));

#define NTOK 4096   // B*S
#define SEQ  1024

__device__ __forceinline__ u16 f2bf(float f){
  union { float f; u32 u; } x; x.f = f;
  u32 r = (x.u + 0x7FFFu + ((x.u >> 16) & 1u)) >> 16;
  return (u16)r;
}
__device__ __forceinline__ float bf2f(u16 u){
  union { u32 u; float f; } x; x.u = ((u32)u) << 16; return x.f;
}
__device__ __forceinline__ void gl_lds16(const void* gp, void* lp){
  __builtin_amdgcn_global_load_lds(
      (const __attribute__((address_space(1))) u32*)gp,
      (__attribute__((address_space(3))) u32*)lp, 16, 0, 0);
}

// ---------------------------------------------------------------- converts
__global__ __launch_bounds__(256) void conv_x(const float* __restrict__ x,
                                              u16* __restrict__ xs, float* __restrict__ xt){
  int t = blockIdx.x * 256 + threadIdx.x;        // < NTOK*1024
  int tok = t >> 10, i = t & 1023;
  xs[t] = f2bf(x[(size_t)tok * 1025 + 1 + i]);
  if (i == 0) xt[tok] = x[(size_t)tok * 1025];
}

__global__ __launch_bounds__(256) void conv_w(const float* __restrict__ W,
                                              u16* __restrict__ Wb, float* __restrict__ w0, int shift){
  int t = blockIdx.x * 256 + threadIdx.x;        // < rows<<shift (exact grid)
  int Kin = 1 << shift;
  int r = t >> shift, i = t & (Kin - 1);
  Wb[t] = f2bf(W[(size_t)r * (Kin + 1) + 1 + i]);
  if (i == 0) w0[r] = W[(size_t)r * (Kin + 1)];
}

// ---------------------------------------------------------------- V transpose (time row from vtm)
// out: vT[(bh*65 + r)*1024 + key]; r=0 is t_v, r=1..64 are feats 0..63
__global__ __launch_bounds__(256) void v_transpose(const u16* __restrict__ qkv,
                                                   const float* __restrict__ vtm,
                                                   u16* __restrict__ vT){
  __shared__ u16 tile[64 * 72];
  const int tid = threadIdx.x;
  const int kt = blockIdx.x, bh = blockIdx.y;
  const int b = bh >> 4, h = bh & 15;
  #pragma unroll
  for (int i = 0; i < 2; i++){
    int c = tid * 2 + i;                          // 0..511
    int key = c >> 3, fc = c & 7;
    uint4 v = *(const uint4*)(qkv + ((size_t)(b * 1024 + kt * 64 + key)) * 3072 + 2048 + h * 64 + fc * 8);
    *(uint4*)&tile[key * 72 + fc * 8] = v;
  }
  __syncthreads();
  for (int c = tid; c < 520; c += 256){
    int vtr = c >> 3, kc = c & 7;
    union { uint4 v; u16 s[8]; } d;
    if (vtr == 0){
      #pragma unroll
      for (int j = 0; j < 8; j++) d.s[j] = f2bf(vtm[(size_t)bh * 1024 + kt * 64 + kc * 8 + j]);
    } else {
      int f = vtr - 1;
      #pragma unroll
      for (int j = 0; j < 8; j++) d.s[j] = tile[(kc * 8 + j) * 72 + f];
    }
    *(uint4*)(vT + ((size_t)bh * 65 + vtr) * 1024 + kt * 64 + kc * 8) = d.v;
  }
}

// ---------------------------------------------------------------- GEMM: C = A(MxK) * B(NxK)^T + at[m]*b0[n] + bias[n]
// at_mode: 0 -> atv=at[m]; 1 -> atv=sqrt(at[m]+1)
// mode 0: QKV (segmented bias, fused per-head time write to qtv/ktv/vtm)
// mode 1: bf16 out at slice offset (split-K partials; bias only on slice 0)
// mode 2: relu -> bf16 out, fused row sum-of-squares atomicAdd into rowsq
__global__ __launch_bounds__(256) void gemm_bt(
    const u16* __restrict__ A, int lda, const u16* __restrict__ Bm, int ldb,
    const float* __restrict__ at, int at_mode, const float* __restrict__ b0,
    const float* __restrict__ bias_a, const float* __restrict__ bias_b, const float* __restrict__ bias_c,
    u16* __restrict__ Cbf, int ldc, int Kslice, int mode,
    float* __restrict__ qtv, float* __restrict__ ktv, float* __restrict__ vtm,
    float* __restrict__ rowsq)
{
  __shared__ u16 As[128 * 32];
  __shared__ u16 Bs[128 * 32];
  const int tid = threadIdx.x;
  const int w = tid >> 6, l = tid & 63;
  const int l15 = l & 15, q = l >> 4;
  const int m0 = blockIdx.y * 128, n0 = blockIdx.x * 128;
  const int ks = blockIdx.z;
  const int kbeg = ks * Kslice;
  const int wr = w >> 1, wc = w & 1;
  f32x4 acc[4][4] = {};
  for (int kt = kbeg; kt < kbeg + Kslice; kt += 32){
    __syncthreads();
    #pragma unroll
    for (int i = 0; i < 2; i++){
      int c = (w * 2 + i) * 64 + l;               // chunk: row=c>>2, kc=c&3
      gl_lds16(A  + (size_t)(m0 + (c >> 2)) * lda + kt + (c & 3) * 8, &As[(w * 2 + i) * 512]);
      gl_lds16(Bm + (size_t)(n0 + (c >> 2)) * ldb + kt + (c & 3) * 8, &Bs[(w * 2 + i) * 512]);
    }
    __syncthreads();
    bf16x8 af[4], bfr[4];
    #pragma unroll
    for (int i = 0; i < 4; i++){
      int row = wr * 64 + i * 16 + l15;
      af[i] = *(const bf16x8*)&As[(row * 4 + q) * 8];
    }
    #pragma unroll
    for (int j = 0; j < 4; j++){
      int row = wc * 64 + j * 16 + l15;
      bfr[j] = *(const bf16x8*)&Bs[(row * 4 + q) * 8];
    }
    #pragma unroll
    for (int i = 0; i < 4; i++)
      #pragma unroll
      for (int j = 0; j < 4; j++)
        acc[i][j] = __builtin_amdgcn_mfma_f32_16x16x32_bf16(af[i], bfr[j], acc[i][j], 0, 0, 0);
  }
  const size_t slice_off = (size_t)ks * (size_t)(gridDim.y * 128) * ldc;
  #pragma unroll
  for (int i = 0; i < 4; i++){
    float atv[4];
    #pragma unroll
    for (int r = 0; r < 4; r++){
      float a = at[m0 + wr * 64 + i * 16 + q * 4 + r];
      atv[r] = at_mode ? sqrtf(a + 1.f) : a;
    }
    float p[4] = {0.f, 0.f, 0.f, 0.f};
    #pragma unroll
    for (int j = 0; j < 4; j++){
      int col = n0 + wc * 64 + j * 16 + l15;
      float b0v = b0[col];
      float bv;
      if (mode == 0) bv = (col < 1024) ? bias_a[col] : (col < 2048) ? bias_b[col - 1024] : bias_c[col - 2048];
      else bv = bias_a[col];
      #pragma unroll
      for (int r = 0; r < 4; r++){
        size_t row = (size_t)(m0 + wr * 64 + i * 16 + q * 4 + r);
        float add = (ks == 0) ? (atv[r] * b0v + bv) : 0.f;
        float v = acc[i][j][r] + add;
        if (mode == 2) v = fmaxf(v, 0.f);
        Cbf[slice_off + row * ldc + col] = f2bf(v);
        if (mode != 1) p[r] += v * v;
      }
    }
    if (mode != 1){
      #pragma unroll
      for (int r = 0; r < 4; r++){
        float s = p[r];
        s += __shfl_xor(s, 1, 64); s += __shfl_xor(s, 2, 64);
        s += __shfl_xor(s, 4, 64); s += __shfl_xor(s, 8, 64);
        if (l15 == 0){
          int row = m0 + wr * 64 + i * 16 + q * 4 + r;
          if (mode == 2){
            atomicAdd(&rowsq[row], s);
          } else {
            int ch = (n0 + wc * 64) >> 6;       // head-chunk 0..47
            int bb = row >> 10, sidx = row & 1023;
            float t = sqrtf(s + 1.f);
            if (ch < 16)      qtv[((size_t)bb * 16 + ch) * 1024 + sidx] = t;
            else if (ch < 32) ktv[((size_t)bb * 16 + ch - 16) * 1024 + sidx] = t;
            else              vtm[((size_t)bb * 16 + ch - 32) * 1024 + sidx] = t;
          }
        }
      }
    }
  }
}

// ---------------------------------------------------------------- flash attention
// grid (S/128, B*H); 512 threads / 8 waves; wave w owns 16 q-rows of a 128-row
// Q tile. Online softmax (softmax denom cancels in lorentz normalize).
// Epilogue atomicAdds sum(out_space^2) per token into aot_sq.
__global__ __launch_bounds__(512) void attn_kernel(
    const u16* __restrict__ qkv, const float* __restrict__ qt,
    const float* __restrict__ ktm, const u16* __restrict__ vT,
    u16* __restrict__ aout, float* __restrict__ aot_sq)
{
  __shared__ u16 Qlds[8192];   // 128 rows x 8 chunks, rotated slots
  __shared__ u16 Klds[4096];   // 64 rows x 8 chunks
  __shared__ u16 Vlds[5120];   // 80 rows x 8 chunks (rows 65..79 garbage, unused cols)
  __shared__ u16 Plds[9216];   // 8 waves x 16 x 72
  const int tid = threadIdx.x;
  const int w = tid >> 6, l = tid & 63;
  const int l15 = l & 15, qd = l >> 4;
  const int q0 = blockIdx.x * 128;
  const int bh = blockIdx.y;
  const int b = bh >> 4, h = bh & 15;
  const size_t tokbase = (size_t)b << 10;

  #pragma unroll
  for (int i = 0; i < 2; i++){
    int c = i * 512 + w * 64 + l;                 // chunk slot 0..1023
    int row = c >> 3, kc = ((c & 7) - row) & 7;   // slot = row*8+((kc+row)&7)
    gl_lds16(qkv + (tokbase + q0 + row) * 3072 + h * 64 + kc * 8, &Qlds[(i * 512 + w * 64) * 8]);
  }
  __syncthreads();
  bf16x8 aq[2];
  {
    int row = w * 16 + l15;
    #pragma unroll
    for (int kk = 0; kk < 2; kk++)
      aq[kk] = *(const bf16x8*)&Qlds[(row * 8 + ((kk * 4 + qd + row) & 7)) * 8];
  }
  float tq[4];
  #pragma unroll
  for (int r = 0; r < 4; r++)
    tq[r] = qt[(size_t)bh * SEQ + q0 + w * 16 + qd * 4 + r];

  float mrow[4] = {-1e30f, -1e30f, -1e30f, -1e30f};
  f32x4 acco[5] = {};

  for (int kt = 0; kt < 16; kt++){
    __syncthreads();
    {
      int c = w * 64 + l;                         // 512 chunks
      int row = c >> 3, kc = ((c & 7) - row) & 7;
      gl_lds16(qkv + (tokbase + kt * 64 + row) * 3072 + 1024 + h * 64 + kc * 8, &Klds[w * 512]);
      gl_lds16(vT + ((size_t)bh * 65 + row) * 1024 + kt * 64 + kc * 8, &Vlds[w * 512]);
    }
    if (w == 0 && l < 8){                          // vT row 64: slots 512..519
      gl_lds16(vT + ((size_t)bh * 65 + 64) * 1024 + kt * 64 + (l & 7) * 8, &Vlds[4096]);
    }
    __syncthreads();

    float sc[4][4];
    float mx[4] = {-1e30f, -1e30f, -1e30f, -1e30f};
    #pragma unroll
    for (int ct = 0; ct < 4; ct++){
      f32x4 z = {0.f, 0.f, 0.f, 0.f};
      int key = ct * 16 + l15;
      #pragma unroll
      for (int kk = 0; kk < 2; kk++){
        bf16x8 bk = *(const bf16x8*)&Klds[(key * 8 + ((kk * 4 + qd + key) & 7)) * 8];
        z = __builtin_amdgcn_mfma_f32_16x16x32_bf16(aq[kk], bk, z, 0, 0, 0);
      }
      float tk = ktm[(size_t)bh * SEQ + kt * 64 + key];
      #pragma unroll
      for (int r = 0; r < 4; r++){
        float s = 0.25f + 0.25f * (z[r] - tq[r] * tk);
        sc[ct][r] = s;
        mx[r] = fmaxf(mx[r], s);
      }
    }
    #pragma unroll
    for (int r = 0; r < 4; r++){
      #pragma unroll
      for (int msk = 1; msk < 16; msk <<= 1)
        mx[r] = fmaxf(mx[r], __shfl_xor(mx[r], msk, 64));
      float mnew = fmaxf(mrow[r], mx[r]);
      float alpha = __expf(mrow[r] - mnew);
      mrow[r] = mnew;
      #pragma unroll
      for (int co = 0; co < 5; co++) acco[co][r] *= alpha;
      mx[r] = mnew;
    }
    #pragma unroll
    for (int ct = 0; ct < 4; ct++)
      #pragma unroll
      for (int r = 0; r < 4; r++)
        Plds[w * 1152 + (qd * 4 + r) * 72 + ct * 16 + l15] = f2bf(__expf(sc[ct][r] - mx[r]));
    asm volatile("s_waitcnt lgkmcnt(0)" ::: "memory");
    bf16x8 ap[2];
    #pragma unroll
    for (int kk = 0; kk < 2; kk++)
      ap[kk] = *(const bf16x8*)&Plds[w * 1152 + l15 * 72 + kk * 32 + qd * 8];
    #pragma unroll
    for (int co = 0; co < 5; co++){
      int vtr = co * 16 + l15;
      #pragma unroll
      for (int kk = 0; kk < 2; kk++){
        bf16x8 bv = *(const bf16x8*)&Vlds[(vtr * 8 + ((kk * 4 + qd + vtr) & 7)) * 8];
        acco[co] = __builtin_amdgcn_mfma_f32_16x16x32_bf16(ap[kk], bv, acco[co], 0, 0, 0);
      }
    }
  }
  #pragma unroll
  for (int r = 0; r < 4; r++){
    float ss = 0.f;
    #pragma unroll
    for (int co = 0; co < 5; co++){
      int col = co * 16 + l15;
      float v = acco[co][r];
      if (col == 0) ss -= v * v;
      else if (col < 65) ss += v * v;
    }
    #pragma unroll
    for (int msk = 1; msk < 16; msk <<= 1) ss += __shfl_xor(ss, msk, 64);
    float v0b = __shfl(acco[0][r], l & 48, 64);       // time comp broadcast in 16-group
    float sp = ss + v0b * v0b;                        // sum of space^2
    float rn = rsqrtf(fmaxf(fabsf(ss), 1e-8f));
    size_t rowg = tokbase + q0 + w * 16 + qd * 4 + r;
    if (l15 == 0) atomicAdd(&aot_sq[rowg], sp * rn * rn);
    #pragma unroll
    for (int co = 0; co < 5; co++){
      int col = co * 16 + l15;
      if (col >= 1 && col < 65)
        aout[rowg * 1024 + h * 64 + col - 1] = f2bf(acco[co][r] * rn);
    }
  }
}

// ---------------------------------------------------------------- midpoint + hyp_layernorm
__device__ __forceinline__ float block_sum(float v, float* red){
  int tid = threadIdx.x;
  #pragma unroll
  for (int m = 1; m < 64; m <<= 1) v += __shfl_xor(v, m, 64);
  __syncthreads();
  if ((tid & 63) == 0) red[tid >> 6] = v;
  __syncthreads();
  return red[0] + red[1] + red[2] + red[3];
}

__global__ __launch_bounds__(256) void mid_ln(
    const u16* __restrict__ z, const float* __restrict__ xfull,
    const u16* __restrict__ xsb, const float* __restrict__ xtv,
    const float* __restrict__ gam, const float* __restrict__ bet,
    u16* __restrict__ ob, float* __restrict__ ot,
    float* __restrict__ ofull, int mode_x, int mode_out, int nsl)
{
  __shared__ float red[4];
  const int tid = threadIdx.x;
  const int tok = blockIdx.x;
  float zv[4], xv[4], xtime;
  if (mode_x == 0){
    const float* xr = xfull + (size_t)tok * 1025;
    xtime = xr[0];
    #pragma unroll
    for (int j = 0; j < 4; j++) xv[j] = xr[1 + tid + j * 256];
  } else {
    xtime = xtv[tok];
    const u16* xr = xsb + (size_t)tok * 1024;
    #pragma unroll
    for (int j = 0; j < 4; j++) xv[j] = bf2f(xr[tid + j * 256]);
  }
  // sum split-K bf16 slices of z
  {
    #pragma unroll
    for (int j = 0; j < 4; j++) zv[j] = 0.f;
    for (int s = 0; s < nsl; s++){
      const u16* zs = z + (size_t)s * NTOK * 1024 + (size_t)tok * 1024;
      #pragma unroll
      for (int j = 0; j < 4; j++) zv[j] += bf2f(zs[tid + j * 256]);
    }
  }
  float ssz = 0.f;
  #pragma unroll
  for (int j = 0; j < 4; j++) ssz += zv[j] * zv[j];
  ssz = block_sum(ssz, red);
  float tz = sqrtf(ssz + 1.f);
  float av[4]; float ssa = 0.f;
  #pragma unroll
  for (int j = 0; j < 4; j++){ av[j] = 0.5f * (zv[j] + xv[j]); ssa += av[j] * av[j]; }
  ssa = block_sum(ssa, red);
  float avt = 0.5f * (tz + xtime);
  float rn = rsqrtf(fmaxf(fabsf(ssa - avt * avt), 1e-8f));
  float uv[4]; float su = 0.f, squ = 0.f;
  #pragma unroll
  for (int j = 0; j < 4; j++){ uv[j] = av[j] * rn; su += uv[j]; squ += uv[j] * uv[j]; }
  su = block_sum(su, red);
  squ = block_sum(squ, red);
  float mu = su * (1.f / 1024.f);
  float var = squ * (1.f / 1024.f) - mu * mu;
  float rv = rsqrtf(fmaxf(var, 0.f) + 1e-5f);
  float sv[4]; float sss = 0.f;
  #pragma unroll
  for (int j = 0; j < 4; j++){
    int i = tid + j * 256;
    sv[j] = (uv[j] - mu) * rv * gam[i] + bet[i];
    sss += sv[j] * sv[j];
  }
  sss = block_sum(sss, red);
  float tout = sqrtf(sss + 1.f);
  if (mode_out == 0){
    #pragma unroll
    for (int j = 0; j < 4; j++){
      int i = tid + j * 256;
      ob[(size_t)tok * 1024 + i] = f2bf(sv[j]);
    }
    if (tid == 0) ot[tok] = tout;
  } else {
    float* orow = ofull + (size_t)tok * 1025;
    #pragma unroll
    for (int j = 0; j < 4; j++) orow[1 + tid + j * 256] = sv[j];
    if (tid == 0) orow[0] = tout;
  }
}

// ---------------------------------------------------------------- launch
extern "C" void kernel_launch(void* const* d_in, const int* in_sizes, int n_in,
                              void* d_out, int out_size, void* d_ws, size_t ws_size,
                              hipStream_t stream){
  const float* x   = (const float*)d_in[0];
  const float* Wq  = (const float*)d_in[1];
  const float* bq  = (const float*)d_in[2];
  const float* Wk  = (const float*)d_in[3];
  const float* bk  = (const float*)d_in[4];
  const float* Wv  = (const float*)d_in[5];
  const float* bv  = (const float*)d_in[6];
  const float* Wo  = (const float*)d_in[7];
  const float* bo  = (const float*)d_in[8];
  const float* g1  = (const float*)d_in[9];
  const float* be1 = (const float*)d_in[10];
  const float* W1  = (const float*)d_in[11];
  const float* c1  = (const float*)d_in[12];
  const float* W2  = (const float*)d_in[13];
  const float* c2  = (const float*)d_in[14];
  const float* g2  = (const float*)d_in[15];
  const float* be2 = (const float*)d_in[16];
  float* out = (float*)d_out;

  char* p = (char*)d_ws;
  auto take = [&](size_t n){ char* r = p; p += (n + 255) & ~(size_t)255; return r; };
  u16*   xs    = (u16*)  take((size_t)NTOK * 1024 * 2);
  float* xt    = (float*)take(NTOK * 4);
  u16*   wqkv  = (u16*)  take((size_t)3072 * 1024 * 2);
  float* wqkv0 = (float*)take(3072 * 4);
  u16*   wo_s  = (u16*)  take((size_t)1024 * 1024 * 2);
  float* wo0   = (float*)take(1024 * 4);
  u16*   w1_s  = (u16*)  take((size_t)4096 * 1024 * 2);
  float* w10   = (float*)take(4096 * 4);
  u16*   w2_s  = (u16*)  take((size_t)1024 * 4096 * 2);
  float* w20   = (float*)take(1024 * 4);
  u16*   qkvb  = (u16*)  take((size_t)NTOK * 3072 * 2);
  float* qtv   = (float*)take((size_t)64 * 1024 * 4);
  float* ktv   = (float*)take((size_t)64 * 1024 * 4);
  float* vtm   = (float*)take((size_t)64 * 1024 * 4);
  u16*   vT    = (u16*)  take((size_t)64 * 65 * 1024 * 2);
  u16*   aoutb = (u16*)  take((size_t)NTOK * 1024 * 2);
  float* sqbuf = (float*)take((size_t)2 * NTOK * 4);   // aot_sq | htv_sq (one memset)
  float* aot_sq = sqbuf;
  float* htv_sq = sqbuf + NTOK;
  u16*   zbuf  = (u16*)  take((size_t)4 * NTOK * 1024 * 2);   // 4 split-K bf16 slices
  u16*   x1b   = (u16*)  take((size_t)NTOK * 1024 * 2);
  float* x1t   = (float*)take(NTOK * 4);
  u16*   hbuf  = (u16*)  take((size_t)NTOK * 4096 * 2);

  hipMemsetAsync(sqbuf, 0, (size_t)2 * NTOK * 4, stream);

  conv_x<<<NTOK * 1024 / 256, 256, 0, stream>>>(x, xs, xt);
  conv_w<<<(1024 * 1024) / 256, 256, 0, stream>>>(Wq, wqkv,               wqkv0,        10);
  conv_w<<<(1024 * 1024) / 256, 256, 0, stream>>>(Wk, wqkv + 1024 * 1024, wqkv0 + 1024, 10);
  conv_w<<<(1024 * 1024) / 256, 256, 0, stream>>>(Wv, wqkv + 2048 * 1024, wqkv0 + 2048, 10);
  conv_w<<<(1024 * 1024) / 256, 256, 0, stream>>>(Wo, wo_s, wo0, 10);
  conv_w<<<(4096 * 1024) / 256, 256, 0, stream>>>(W1, w1_s, w10, 10);
  conv_w<<<(1024 * 4096) / 256, 256, 0, stream>>>(W2, w2_s, w20, 12);

  // QKV + fused per-head time norms
  gemm_bt<<<dim3(24, 32), 256, 0, stream>>>(xs, 1024, wqkv, 1024, xt, 0, wqkv0,
      bq, bk, bv, qkvb, 3072, 1024, 0, qtv, ktv, vtm, nullptr);
  v_transpose<<<dim3(16, 64), 256, 0, stream>>>(qkvb, vtm, vT);
  attn_kernel<<<dim3(8, 64), 512, 0, stream>>>(qkvb, qtv, ktv, vT, aoutb, aot_sq);
  // O-proj: split-K x2, bf16 partial slices
  gemm_bt<<<dim3(8, 32, 2), 256, 0, stream>>>(aoutb, 1024, wo_s, 1024, aot_sq, 1, wo0,
      bo, nullptr, nullptr, zbuf, 1024, 512, 1, nullptr, nullptr, nullptr, nullptr);
  mid_ln<<<NTOK, 256, 0, stream>>>(zbuf, x, nullptr, nullptr, g1, be1,
      x1b, x1t, nullptr, 0, 0, 2);
  // MLP1 + relu + fused row sum-of-squares
  gemm_bt<<<dim3(32, 32), 256, 0, stream>>>(x1b, 1024, w1_s, 1024, x1t, 0, w10,
      c1, nullptr, nullptr, hbuf, 4096, 1024, 2, nullptr, nullptr, nullptr, htv_sq);
  // MLP2: split-K x4, bf16 partial slices
  gemm_bt<<<dim3(8, 32, 4), 256, 0, stream>>>(hbuf, 4096, w2_s, 4096, htv_sq, 1, w20,
      c2, nullptr, nullptr, zbuf, 1024, 1024, 1, nullptr, nullptr, nullptr, nullptr);
  mid_ln<<<NTOK, 256, 0, stream>>>(zbuf, nullptr, x1b, x1t, g2, be2,
      nullptr, nullptr, out, 1, 1, 4);
}

// Round 5
// 478.421 us; speedup vs baseline: 4.5709x; 1.0119x over previous
//
#include <hip/hip_runtime.h>

typedef unsigned short u16;
typedef unsigned int   u32;
typedef short bf16x8 __attribute__((ext_vector_type(8)));
typedef float f32x4  __attribute__((ext_vector_type(4)));

#define NTOK 4096   // B*S
#define SEQ  1024

__device__ __forceinline__ u16 f2bf(float f){
  union { float f; u32 u; } x; x.f = f;
  u32 r = (x.u + 0x7FFFu + ((x.u >> 16) & 1u)) >> 16;
  return (u16)r;
}
__device__ __forceinline__ float bf2f(u16 u){
  union { u32 u; float f; } x; x.u = ((u32)u) << 16; return x.f;
}
__device__ __forceinline__ void gl_lds16(const void* gp, void* lp){
  __builtin_amdgcn_global_load_lds(
      (const __attribute__((address_space(1))) u32*)gp,
      (__attribute__((address_space(3))) u32*)lp, 16, 0, 0);
}

// ---------------------------------------------------------------- converts
__global__ __launch_bounds__(256) void conv_x(const float* __restrict__ x,
                                              u16* __restrict__ xs, float* __restrict__ xt){
  int t = blockIdx.x * 256 + threadIdx.x;        // < NTOK*1024
  int tok = t >> 10, i = t & 1023;
  xs[t] = f2bf(x[(size_t)tok * 1025 + 1 + i]);
  if (i == 0) xt[tok] = x[(size_t)tok * 1025];
}

__global__ __launch_bounds__(256) void conv_w(const float* __restrict__ W,
                                              u16* __restrict__ Wb, float* __restrict__ w0, int shift){
  int t = blockIdx.x * 256 + threadIdx.x;        // < rows<<shift (exact grid)
  int Kin = 1 << shift;
  int r = t >> shift, i = t & (Kin - 1);
  Wb[t] = f2bf(W[(size_t)r * (Kin + 1) + 1 + i]);
  if (i == 0) w0[r] = W[(size_t)r * (Kin + 1)];
}

// ---------------------------------------------------------------- V transpose (time row from vtm)
// out: vT[(bh*65 + r)*1024 + key]; r=0 is t_v, r=1..64 are feats 0..63
__global__ __launch_bounds__(256) void v_transpose(const u16* __restrict__ qkv,
                                                   const float* __restrict__ vtm,
                                                   u16* __restrict__ vT){
  __shared__ u16 tile[64 * 72];
  const int tid = threadIdx.x;
  const int kt = blockIdx.x, bh = blockIdx.y;
  const int b = bh >> 4, h = bh & 15;
  #pragma unroll
  for (int i = 0; i < 2; i++){
    int c = tid * 2 + i;                          // 0..511
    int key = c >> 3, fc = c & 7;
    uint4 v = *(const uint4*)(qkv + ((size_t)(b * 1024 + kt * 64 + key)) * 3072 + 2048 + h * 64 + fc * 8);
    *(uint4*)&tile[key * 72 + fc * 8] = v;
  }
  __syncthreads();
  for (int c = tid; c < 520; c += 256){
    int vtr = c >> 3, kc = c & 7;
    union { uint4 v; u16 s[8]; } d;
    if (vtr == 0){
      #pragma unroll
      for (int j = 0; j < 8; j++) d.s[j] = f2bf(vtm[(size_t)bh * 1024 + kt * 64 + kc * 8 + j]);
    } else {
      int f = vtr - 1;
      #pragma unroll
      for (int j = 0; j < 8; j++) d.s[j] = tile[(kc * 8 + j) * 72 + f];
    }
    *(uint4*)(vT + ((size_t)bh * 65 + vtr) * 1024 + kt * 64 + kc * 8) = d.v;
  }
}

// ---------------------------------------------------------------- GEMM: C = A(MxK) * B(NxK)^T + at[m]*b0[n] + bias[n]
// LDS layout swizzled: chunk(row,kc of 4) -> slot row*4 + ((kc + (row>>1)) & 3)
// so 16-lane fragment reads cover all 8 bank-quads (2-way = free).
// at_mode: 0 -> atv=at[m]; 1 -> atv=sqrt(at[m]+1)
// mode 0: QKV (segmented bias, fused per-head time write to qtv/ktv/vtm)
// mode 1: bf16 out at slice offset (split-K partials; bias only on slice 0)
// mode 2: relu -> bf16 out, fused row sum-of-squares atomicAdd into rowsq
__global__ __launch_bounds__(256) void gemm_bt(
    const u16* __restrict__ A, int lda, const u16* __restrict__ Bm, int ldb,
    const float* __restrict__ at, int at_mode, const float* __restrict__ b0,
    const float* __restrict__ bias_a, const float* __restrict__ bias_b, const float* __restrict__ bias_c,
    u16* __restrict__ Cbf, int ldc, int Kslice, int mode,
    float* __restrict__ qtv, float* __restrict__ ktv, float* __restrict__ vtm,
    float* __restrict__ rowsq)
{
  __shared__ u16 As[128 * 32];
  __shared__ u16 Bs[128 * 32];
  const int tid = threadIdx.x;
  const int w = tid >> 6, l = tid & 63;
  const int l15 = l & 15, q = l >> 4;
  const int m0 = blockIdx.y * 128, n0 = blockIdx.x * 128;
  const int ks = blockIdx.z;
  const int kbeg = ks * Kslice;
  const int wr = w >> 1, wc = w & 1;
  f32x4 acc[4][4] = {};
  for (int kt = kbeg; kt < kbeg + Kslice; kt += 32){
    __syncthreads();
    #pragma unroll
    for (int i = 0; i < 2; i++){
      int s = (w * 2 + i) * 64 + l;               // LDS slot 0..511
      int row = s >> 2;
      int kc = ((s & 3) - (s >> 3)) & 3;          // invert swizzle
      gl_lds16(A  + (size_t)(m0 + row) * lda + kt + kc * 8, &As[(w * 2 + i) * 512]);
      gl_lds16(Bm + (size_t)(n0 + row) * ldb + kt + kc * 8, &Bs[(w * 2 + i) * 512]);
    }
    __syncthreads();
    bf16x8 af[4], bfr[4];
    #pragma unroll
    for (int i = 0; i < 4; i++){
      int row = wr * 64 + i * 16 + l15;
      int slot = row * 4 + ((q + (row >> 1)) & 3);
      af[i] = *(const bf16x8*)&As[slot * 8];
    }
    #pragma unroll
    for (int j = 0; j < 4; j++){
      int row = wc * 64 + j * 16 + l15;
      int slot = row * 4 + ((q + (row >> 1)) & 3);
      bfr[j] = *(const bf16x8*)&Bs[slot * 8];
    }
    #pragma unroll
    for (int i = 0; i < 4; i++)
      #pragma unroll
      for (int j = 0; j < 4; j++)
        acc[i][j] = __builtin_amdgcn_mfma_f32_16x16x32_bf16(af[i], bfr[j], acc[i][j], 0, 0, 0);
  }
  const size_t slice_off = (size_t)ks * (size_t)(gridDim.y * 128) * ldc;
  #pragma unroll
  for (int i = 0; i < 4; i++){
    float atv[4];
    #pragma unroll
    for (int r = 0; r < 4; r++){
      float a = at[m0 + wr * 64 + i * 16 + q * 4 + r];
      atv[r] = at_mode ? sqrtf(a + 1.f) : a;
    }
    float p[4] = {0.f, 0.f, 0.f, 0.f};
    #pragma unroll
    for (int j = 0; j < 4; j++){
      int col = n0 + wc * 64 + j * 16 + l15;
      float b0v = b0[col];
      float bv;
      if (mode == 0) bv = (col < 1024) ? bias_a[col] : (col < 2048) ? bias_b[col - 1024] : bias_c[col - 2048];
      else bv = bias_a[col];
      #pragma unroll
      for (int r = 0; r < 4; r++){
        size_t row = (size_t)(m0 + wr * 64 + i * 16 + q * 4 + r);
        float add = (ks == 0) ? (atv[r] * b0v + bv) : 0.f;
        float v = acc[i][j][r] + add;
        if (mode == 2) v = fmaxf(v, 0.f);
        Cbf[slice_off + row * ldc + col] = f2bf(v);
        if (mode != 1) p[r] += v * v;
      }
    }
    if (mode != 1){
      #pragma unroll
      for (int r = 0; r < 4; r++){
        float s = p[r];
        s += __shfl_xor(s, 1, 64); s += __shfl_xor(s, 2, 64);
        s += __shfl_xor(s, 4, 64); s += __shfl_xor(s, 8, 64);
        if (l15 == 0){
          int row = m0 + wr * 64 + i * 16 + q * 4 + r;
          if (mode == 2){
            atomicAdd(&rowsq[row], s);
          } else {
            int ch = (n0 + wc * 64) >> 6;       // head-chunk 0..47
            int bb = row >> 10, sidx = row & 1023;
            float t = sqrtf(s + 1.f);
            if (ch < 16)      qtv[((size_t)bb * 16 + ch) * 1024 + sidx] = t;
            else if (ch < 32) ktv[((size_t)bb * 16 + ch - 16) * 1024 + sidx] = t;
            else              vtm[((size_t)bb * 16 + ch - 32) * 1024 + sidx] = t;
          }
        }
      }
    }
  }
}

// ---------------------------------------------------------------- flash attention
// grid (S/128, B*H); 512 threads / 8 waves; wave w owns 16 q-rows of a 128-row
// Q tile. Online softmax (softmax denom cancels in lorentz normalize).
// Epilogue atomicAdds sum(out_space^2) per token into aot_sq.
__global__ __launch_bounds__(512) void attn_kernel(
    const u16* __restrict__ qkv, const float* __restrict__ qt,
    const float* __restrict__ ktm, const u16* __restrict__ vT,
    u16* __restrict__ aout, float* __restrict__ aot_sq)
{
  __shared__ u16 Qlds[8192];   // 128 rows x 8 chunks, rotated slots
  __shared__ u16 Klds[4096];   // 64 rows x 8 chunks
  __shared__ u16 Vlds[5120];   // 80 rows x 8 chunks (rows 65..79 garbage, unused cols)
  __shared__ u16 Plds[9216];   // 8 waves x 16 x 72
  const int tid = threadIdx.x;
  const int w = tid >> 6, l = tid & 63;
  const int l15 = l & 15, qd = l >> 4;
  const int q0 = blockIdx.x * 128;
  const int bh = blockIdx.y;
  const int b = bh >> 4, h = bh & 15;
  const size_t tokbase = (size_t)b << 10;

  #pragma unroll
  for (int i = 0; i < 2; i++){
    int c = i * 512 + w * 64 + l;                 // chunk slot 0..1023
    int row = c >> 3, kc = ((c & 7) - row) & 7;   // slot = row*8+((kc+row)&7)
    gl_lds16(qkv + (tokbase + q0 + row) * 3072 + h * 64 + kc * 8, &Qlds[(i * 512 + w * 64) * 8]);
  }
  __syncthreads();
  bf16x8 aq[2];
  {
    int row = w * 16 + l15;
    #pragma unroll
    for (int kk = 0; kk < 2; kk++)
      aq[kk] = *(const bf16x8*)&Qlds[(row * 8 + ((kk * 4 + qd + row) & 7)) * 8];
  }
  float tq[4];
  #pragma unroll
  for (int r = 0; r < 4; r++)
    tq[r] = qt[(size_t)bh * SEQ + q0 + w * 16 + qd * 4 + r];

  float mrow[4] = {-1e30f, -1e30f, -1e30f, -1e30f};
  f32x4 acco[5] = {};

  for (int kt = 0; kt < 16; kt++){
    __syncthreads();
    {
      int c = w * 64 + l;                         // 512 chunks
      int row = c >> 3, kc = ((c & 7) - row) & 7;
      gl_lds16(qkv + (tokbase + kt * 64 + row) * 3072 + 1024 + h * 64 + kc * 8, &Klds[w * 512]);
      gl_lds16(vT + ((size_t)bh * 65 + row) * 1024 + kt * 64 + kc * 8, &Vlds[w * 512]);
    }
    if (w == 0 && l < 8){                          // vT row 64: slots 512..519
      gl_lds16(vT + ((size_t)bh * 65 + 64) * 1024 + kt * 64 + (l & 7) * 8, &Vlds[4096]);
    }
    __syncthreads();

    float sc[4][4];
    float mx[4] = {-1e30f, -1e30f, -1e30f, -1e30f};
    #pragma unroll
    for (int ct = 0; ct < 4; ct++){
      f32x4 z = {0.f, 0.f, 0.f, 0.f};
      int key = ct * 16 + l15;
      #pragma unroll
      for (int kk = 0; kk < 2; kk++){
        bf16x8 bk = *(const bf16x8*)&Klds[(key * 8 + ((kk * 4 + qd + key) & 7)) * 8];
        z = __builtin_amdgcn_mfma_f32_16x16x32_bf16(aq[kk], bk, z, 0, 0, 0);
      }
      float tk = ktm[(size_t)bh * SEQ + kt * 64 + key];
      #pragma unroll
      for (int r = 0; r < 4; r++){
        float s = 0.25f + 0.25f * (z[r] - tq[r] * tk);
        sc[ct][r] = s;
        mx[r] = fmaxf(mx[r], s);
      }
    }
    #pragma unroll
    for (int r = 0; r < 4; r++){
      #pragma unroll
      for (int msk = 1; msk < 16; msk <<= 1)
        mx[r] = fmaxf(mx[r], __shfl_xor(mx[r], msk, 64));
      float mnew = fmaxf(mrow[r], mx[r]);
      float alpha = __expf(mrow[r] - mnew);
      mrow[r] = mnew;
      #pragma unroll
      for (int co = 0; co < 5; co++) acco[co][r] *= alpha;
      mx[r] = mnew;
    }
    #pragma unroll
    for (int ct = 0; ct < 4; ct++)
      #pragma unroll
      for (int r = 0; r < 4; r++)
        Plds[w * 1152 + (qd * 4 + r) * 72 + ct * 16 + l15] = f2bf(__expf(sc[ct][r] - mx[r]));
    asm volatile("s_waitcnt lgkmcnt(0)" ::: "memory");
    bf16x8 ap[2];
    #pragma unroll
    for (int kk = 0; kk < 2; kk++)
      ap[kk] = *(const bf16x8*)&Plds[w * 1152 + l15 * 72 + kk * 32 + qd * 8];
    #pragma unroll
    for (int co = 0; co < 5; co++){
      int vtr = co * 16 + l15;
      #pragma unroll
      for (int kk = 0; kk < 2; kk++){
        bf16x8 bv = *(const bf16x8*)&Vlds[(vtr * 8 + ((kk * 4 + qd + vtr) & 7)) * 8];
        acco[co] = __builtin_amdgcn_mfma_f32_16x16x32_bf16(ap[kk], bv, acco[co], 0, 0, 0);
      }
    }
  }
  #pragma unroll
  for (int r = 0; r < 4; r++){
    float ss = 0.f;
    #pragma unroll
    for (int co = 0; co < 5; co++){
      int col = co * 16 + l15;
      float v = acco[co][r];
      if (col == 0) ss -= v * v;
      else if (col < 65) ss += v * v;
    }
    #pragma unroll
    for (int msk = 1; msk < 16; msk <<= 1) ss += __shfl_xor(ss, msk, 64);
    float v0b = __shfl(acco[0][r], l & 48, 64);       // time comp broadcast in 16-group
    float sp = ss + v0b * v0b;                        // sum of space^2
    float rn = rsqrtf(fmaxf(fabsf(ss), 1e-8f));
    size_t rowg = tokbase + q0 + w * 16 + qd * 4 + r;
    if (l15 == 0) atomicAdd(&aot_sq[rowg], sp * rn * rn);
    #pragma unroll
    for (int co = 0; co < 5; co++){
      int col = co * 16 + l15;
      if (col >= 1 && col < 65)
        aout[rowg * 1024 + h * 64 + col - 1] = f2bf(acco[co][r] * rn);
    }
  }
}

// ---------------------------------------------------------------- midpoint + hyp_layernorm
__device__ __forceinline__ float block_sum(float v, float* red){
  int tid = threadIdx.x;
  #pragma unroll
  for (int m = 1; m < 64; m <<= 1) v += __shfl_xor(v, m, 64);
  __syncthreads();
  if ((tid & 63) == 0) red[tid >> 6] = v;
  __syncthreads();
  return red[0] + red[1] + red[2] + red[3];
}

__global__ __launch_bounds__(256) void mid_ln(
    const u16* __restrict__ z, const float* __restrict__ xfull,
    const u16* __restrict__ xsb, const float* __restrict__ xtv,
    const float* __restrict__ gam, const float* __restrict__ bet,
    u16* __restrict__ ob, float* __restrict__ ot,
    float* __restrict__ ofull, int mode_x, int mode_out, int nsl)
{
  __shared__ float red[4];
  const int tid = threadIdx.x;
  const int tok = blockIdx.x;
  float zv[4], xv[4], xtime;
  if (mode_x == 0){
    const float* xr = xfull + (size_t)tok * 1025;
    xtime = xr[0];
    #pragma unroll
    for (int j = 0; j < 4; j++) xv[j] = xr[1 + tid + j * 256];
  } else {
    xtime = xtv[tok];
    const u16* xr = xsb + (size_t)tok * 1024;
    #pragma unroll
    for (int j = 0; j < 4; j++) xv[j] = bf2f(xr[tid + j * 256]);
  }
  // sum split-K bf16 slices of z
  {
    #pragma unroll
    for (int j = 0; j < 4; j++) zv[j] = 0.f;
    for (int s = 0; s < nsl; s++){
      const u16* zs = z + (size_t)s * NTOK * 1024 + (size_t)tok * 1024;
      #pragma unroll
      for (int j = 0; j < 4; j++) zv[j] += bf2f(zs[tid + j * 256]);
    }
  }
  float ssz = 0.f;
  #pragma unroll
  for (int j = 0; j < 4; j++) ssz += zv[j] * zv[j];
  ssz = block_sum(ssz, red);
  float tz = sqrtf(ssz + 1.f);
  float av[4]; float ssa = 0.f;
  #pragma unroll
  for (int j = 0; j < 4; j++){ av[j] = 0.5f * (zv[j] + xv[j]); ssa += av[j] * av[j]; }
  ssa = block_sum(ssa, red);
  float avt = 0.5f * (tz + xtime);
  float rn = rsqrtf(fmaxf(fabsf(ssa - avt * avt), 1e-8f));
  float uv[4]; float su = 0.f, squ = 0.f;
  #pragma unroll
  for (int j = 0; j < 4; j++){ uv[j] = av[j] * rn; su += uv[j]; squ += uv[j] * uv[j]; }
  su = block_sum(su, red);
  squ = block_sum(squ, red);
  float mu = su * (1.f / 1024.f);
  float var = squ * (1.f / 1024.f) - mu * mu;
  float rv = rsqrtf(fmaxf(var, 0.f) + 1e-5f);
  float sv[4]; float sss = 0.f;
  #pragma unroll
  for (int j = 0; j < 4; j++){
    int i = tid + j * 256;
    sv[j] = (uv[j] - mu) * rv * gam[i] + bet[i];
    sss += sv[j] * sv[j];
  }
  sss = block_sum(sss, red);
  float tout = sqrtf(sss + 1.f);
  if (mode_out == 0){
    #pragma unroll
    for (int j = 0; j < 4; j++){
      int i = tid + j * 256;
      ob[(size_t)tok * 1024 + i] = f2bf(sv[j]);
    }
    if (tid == 0) ot[tok] = tout;
  } else {
    float* orow = ofull + (size_t)tok * 1025;
    #pragma unroll
    for (int j = 0; j < 4; j++) orow[1 + tid + j * 256] = sv[j];
    if (tid == 0) orow[0] = tout;
  }
}

// ---------------------------------------------------------------- launch
extern "C" void kernel_launch(void* const* d_in, const int* in_sizes, int n_in,
                              void* d_out, int out_size, void* d_ws, size_t ws_size,
                              hipStream_t stream){
  const float* x   = (const float*)d_in[0];
  const float* Wq  = (const float*)d_in[1];
  const float* bq  = (const float*)d_in[2];
  const float* Wk  = (const float*)d_in[3];
  const float* bk  = (const float*)d_in[4];
  const float* Wv  = (const float*)d_in[5];
  const float* bv  = (const float*)d_in[6];
  const float* Wo  = (const float*)d_in[7];
  const float* bo  = (const float*)d_in[8];
  const float* g1  = (const float*)d_in[9];
  const float* be1 = (const float*)d_in[10];
  const float* W1  = (const float*)d_in[11];
  const float* c1  = (const float*)d_in[12];
  const float* W2  = (const float*)d_in[13];
  const float* c2  = (const float*)d_in[14];
  const float* g2  = (const float*)d_in[15];
  const float* be2 = (const float*)d_in[16];
  float* out = (float*)d_out;

  char* p = (char*)d_ws;
  auto take = [&](size_t n){ char* r = p; p += (n + 255) & ~(size_t)255; return r; };
  u16*   xs    = (u16*)  take((size_t)NTOK * 1024 * 2);
  float* xt    = (float*)take(NTOK * 4);
  u16*   wqkv  = (u16*)  take((size_t)3072 * 1024 * 2);
  float* wqkv0 = (float*)take(3072 * 4);
  u16*   wo_s  = (u16*)  take((size_t)1024 * 1024 * 2);
  float* wo0   = (float*)take(1024 * 4);
  u16*   w1_s  = (u16*)  take((size_t)4096 * 1024 * 2);
  float* w10   = (float*)take(4096 * 4);
  u16*   w2_s  = (u16*)  take((size_t)1024 * 4096 * 2);
  float* w20   = (float*)take(1024 * 4);
  u16*   qkvb  = (u16*)  take((size_t)NTOK * 3072 * 2);
  float* qtv   = (float*)take((size_t)64 * 1024 * 4);
  float* ktv   = (float*)take((size_t)64 * 1024 * 4);
  float* vtm   = (float*)take((size_t)64 * 1024 * 4);
  u16*   vT    = (u16*)  take((size_t)64 * 65 * 1024 * 2);
  u16*   aoutb = (u16*)  take((size_t)NTOK * 1024 * 2);
  float* sqbuf = (float*)take((size_t)2 * NTOK * 4);   // aot_sq | htv_sq (one memset)
  float* aot_sq = sqbuf;
  float* htv_sq = sqbuf + NTOK;
  u16*   zbuf  = (u16*)  take((size_t)4 * NTOK * 1024 * 2);   // 4 split-K bf16 slices
  u16*   x1b   = (u16*)  take((size_t)NTOK * 1024 * 2);
  float* x1t   = (float*)take(NTOK * 4);
  u16*   hbuf  = (u16*)  take((size_t)NTOK * 4096 * 2);

  hipMemsetAsync(sqbuf, 0, (size_t)2 * NTOK * 4, stream);

  conv_x<<<NTOK * 1024 / 256, 256, 0, stream>>>(x, xs, xt);
  conv_w<<<(1024 * 1024) / 256, 256, 0, stream>>>(Wq, wqkv,               wqkv0,        10);
  conv_w<<<(1024 * 1024) / 256, 256, 0, stream>>>(Wk, wqkv + 1024 * 1024, wqkv0 + 1024, 10);
  conv_w<<<(1024 * 1024) / 256, 256, 0, stream>>>(Wv, wqkv + 2048 * 1024, wqkv0 + 2048, 10);
  conv_w<<<(1024 * 1024) / 256, 256, 0, stream>>>(Wo, wo_s, wo0, 10);
  conv_w<<<(4096 * 1024) / 256, 256, 0, stream>>>(W1, w1_s, w10, 10);
  conv_w<<<(1024 * 4096) / 256, 256, 0, stream>>>(W2, w2_s, w20, 12);

  // QKV + fused per-head time norms
  gemm_bt<<<dim3(24, 32), 256, 0, stream>>>(xs, 1024, wqkv, 1024, xt, 0, wqkv0,
      bq, bk, bv, qkvb, 3072, 1024, 0, qtv, ktv, vtm, nullptr);
  v_transpose<<<dim3(16, 64), 256, 0, stream>>>(qkvb, vtm, vT);
  attn_kernel<<<dim3(8, 64), 512, 0, stream>>>(qkvb, qtv, ktv, vT, aoutb, aot_sq);
  // O-proj: split-K x2, bf16 partial slices
  gemm_bt<<<dim3(8, 32, 2), 256, 0, stream>>>(aoutb, 1024, wo_s, 1024, aot_sq, 1, wo0,
      bo, nullptr, nullptr, zbuf, 1024, 512, 1, nullptr, nullptr, nullptr, nullptr);
  mid_ln<<<NTOK, 256, 0, stream>>>(zbuf, x, nullptr, nullptr, g1, be1,
      x1b, x1t, nullptr, 0, 0, 2);
  // MLP1 + relu + fused row sum-of-squares
  gemm_bt<<<dim3(32, 32), 256, 0, stream>>>(x1b, 1024, w1_s, 1024, x1t, 0, w10,
      c1, nullptr, nullptr, hbuf, 4096, 1024, 2, nullptr, nullptr, nullptr, htv_sq);
  // MLP2: split-K x4, bf16 partial slices
  gemm_bt<<<dim3(8, 32, 4), 256, 0, stream>>>(hbuf, 4096, w2_s, 4096, htv_sq, 1, w20,
      c2, nullptr, nullptr, zbuf, 1024, 1024, 1, nullptr, nullptr, nullptr, nullptr);
  mid_ln<<<NTOK, 256, 0, stream>>>(zbuf, nullptr, x1b, x1t, g2, be2,
      nullptr, nullptr, out, 1, 1, 4);
}

// Round 6
// 448.264 us; speedup vs baseline: 4.8784x; 1.0673x over previous
//
#include <hip/hip_runtime.h>

typedef unsigned short u16;
typedef unsigned int   u32;
typedef short bf16x8 __attribute__((ext_vector_type(8)));
typedef float f32x4  __attribute__((ext_vector_type(4)));

#define NTOK 4096   // B*S
#define SEQ  1024

__device__ __forceinline__ u16 f2bf(float f){
  union { float f; u32 u; } x; x.f = f;
  u32 r = (x.u + 0x7FFFu + ((x.u >> 16) & 1u)) >> 16;
  return (u16)r;
}
__device__ __forceinline__ float bf2f(u16 u){
  union { u32 u; float f; } x; x.u = ((u32)u) << 16; return x.f;
}
__device__ __forceinline__ void gl_lds16(const void* gp, void* lp){
  __builtin_amdgcn_global_load_lds(
      (const __attribute__((address_space(1))) u32*)gp,
      (__attribute__((address_space(3))) u32*)lp, 16, 0, 0);
}

// ---------------------------------------------------------------- converts
__global__ __launch_bounds__(256) void conv_x(const float* __restrict__ x,
                                              u16* __restrict__ xs, float* __restrict__ xt){
  int t = blockIdx.x * 256 + threadIdx.x;        // < NTOK*1024
  int tok = t >> 10, i = t & 1023;
  xs[t] = f2bf(x[(size_t)tok * 1025 + 1 + i]);
  if (i == 0) xt[tok] = x[(size_t)tok * 1025];
}

// all six weight converts in one launch; region branches are wave-uniform
__global__ __launch_bounds__(256) void conv_w_all(
    const float* __restrict__ Wq, const float* __restrict__ Wk,
    const float* __restrict__ Wv, const float* __restrict__ Wo,
    const float* __restrict__ W1, const float* __restrict__ W2,
    u16* __restrict__ wqkv, u16* __restrict__ wo_s, u16* __restrict__ w1_s, u16* __restrict__ w2_s,
    float* __restrict__ wqkv0, float* __restrict__ wo0, float* __restrict__ w10, float* __restrict__ w20)
{
  int t = blockIdx.x * 256 + threadIdx.x;   // < 12*1024*1024
  const int M1 = 1 << 20;
  const float* W; u16* Wb; float* w0; int shift; int idx;
  if (t < 4 * M1){
    int region = t >> 20; idx = t & (M1 - 1); shift = 10;
    if (region == 0)      { W = Wq; Wb = wqkv;          w0 = wqkv0; }
    else if (region == 1) { W = Wk; Wb = wqkv + M1;     w0 = wqkv0 + 1024; }
    else if (region == 2) { W = Wv; Wb = wqkv + 2 * M1; w0 = wqkv0 + 2048; }
    else                  { W = Wo; Wb = wo_s;          w0 = wo0; }
  } else if (t < 8 * M1){
    idx = t - 4 * M1; shift = 10; W = W1; Wb = w1_s; w0 = w10;
  } else {
    idx = t - 8 * M1; shift = 12; W = W2; Wb = w2_s; w0 = w20;
  }
  int Kin = 1 << shift;
  int r = idx >> shift, i = idx & (Kin - 1);
  Wb[idx] = f2bf(W[(size_t)r * (Kin + 1) + 1 + i]);
  if (i == 0) w0[r] = W[(size_t)r * (Kin + 1)];
}

// ---------------------------------------------------------------- V transpose (time row from vtm)
// out: vT[(bh*65 + r)*1024 + key]; r=0 is t_v, r=1..64 are feats 0..63
__global__ __launch_bounds__(256) void v_transpose(const u16* __restrict__ qkv,
                                                   const float* __restrict__ vtm,
                                                   u16* __restrict__ vT){
  __shared__ u16 tile[64 * 72];
  const int tid = threadIdx.x;
  const int kt = blockIdx.x, bh = blockIdx.y;
  const int b = bh >> 4, h = bh & 15;
  #pragma unroll
  for (int i = 0; i < 2; i++){
    int c = tid * 2 + i;                          // 0..511
    int key = c >> 3, fc = c & 7;
    uint4 v = *(const uint4*)(qkv + ((size_t)(b * 1024 + kt * 64 + key)) * 3072 + 2048 + h * 64 + fc * 8);
    *(uint4*)&tile[key * 72 + fc * 8] = v;
  }
  __syncthreads();
  for (int c = tid; c < 520; c += 256){
    int vtr = c >> 3, kc = c & 7;
    union { uint4 v; u16 s[8]; } d;
    if (vtr == 0){
      #pragma unroll
      for (int j = 0; j < 8; j++) d.s[j] = f2bf(vtm[(size_t)bh * 1024 + kt * 64 + kc * 8 + j]);
    } else {
      int f = vtr - 1;
      #pragma unroll
      for (int j = 0; j < 8; j++) d.s[j] = tile[(kc * 8 + j) * 72 + f];
    }
    *(uint4*)(vT + ((size_t)bh * 65 + vtr) * 1024 + kt * 64 + kc * 8) = d.v;
  }
}

// ---------------------------------------------------------------- GEMM: C = A(MxK) * B(NxK)^T + at[m]*b0[n] + bias[n]
// Double-buffered LDS ping-pong: one barrier per 32-K chunk; loads for tile
// k+1 issued right after the barrier, compute on the other buffer covers the
// vmcnt drain. LDS swizzle (conflict-free) kept from r5.
// at_mode: 0 -> atv=at[m]; 1 -> atv=sqrt(at[m]+1)
// mode 0: QKV (segmented bias, fused per-head time write to qtv/ktv/vtm)
// mode 1: bf16 out at slice offset (split-K partials; bias only on slice 0)
// mode 2: relu -> bf16 out, fused row sum-of-squares atomicAdd into rowsq
__global__ __launch_bounds__(256) void gemm_bt(
    const u16* __restrict__ A, int lda, const u16* __restrict__ Bm, int ldb,
    const float* __restrict__ at, int at_mode, const float* __restrict__ b0,
    const float* __restrict__ bias_a, const float* __restrict__ bias_b, const float* __restrict__ bias_c,
    u16* __restrict__ Cbf, int ldc, int Kslice, int mode,
    float* __restrict__ qtv, float* __restrict__ ktv, float* __restrict__ vtm,
    float* __restrict__ rowsq)
{
  __shared__ u16 As[2][128 * 32];
  __shared__ u16 Bs[2][128 * 32];
  const int tid = threadIdx.x;
  const int w = tid >> 6, l = tid & 63;
  const int l15 = l & 15, q = l >> 4;
  const int m0 = blockIdx.y * 128, n0 = blockIdx.x * 128;
  const int ks = blockIdx.z;
  const int kbeg = ks * Kslice;
  const int kend = kbeg + Kslice;
  const int wr = w >> 1, wc = w & 1;
  f32x4 acc[4][4] = {};

  auto stage = [&](int kt, int buf){
    #pragma unroll
    for (int i = 0; i < 2; i++){
      int s = (w * 2 + i) * 64 + l;               // LDS slot 0..511
      int row = s >> 2;
      int kc = ((s & 3) - (s >> 3)) & 3;          // invert swizzle
      gl_lds16(A  + (size_t)(m0 + row) * lda + kt + kc * 8, &As[buf][(w * 2 + i) * 512]);
      gl_lds16(Bm + (size_t)(n0 + row) * ldb + kt + kc * 8, &Bs[buf][(w * 2 + i) * 512]);
    }
  };
  auto compute = [&](int buf){
    bf16x8 af[4], bfr[4];
    #pragma unroll
    for (int i = 0; i < 4; i++){
      int row = wr * 64 + i * 16 + l15;
      int slot = row * 4 + ((q + (row >> 1)) & 3);
      af[i] = *(const bf16x8*)&As[buf][slot * 8];
    }
    #pragma unroll
    for (int j = 0; j < 4; j++){
      int row = wc * 64 + j * 16 + l15;
      int slot = row * 4 + ((q + (row >> 1)) & 3);
      bfr[j] = *(const bf16x8*)&Bs[buf][slot * 8];
    }
    #pragma unroll
    for (int i = 0; i < 4; i++)
      #pragma unroll
      for (int j = 0; j < 4; j++)
        acc[i][j] = __builtin_amdgcn_mfma_f32_16x16x32_bf16(af[i], bfr[j], acc[i][j], 0, 0, 0);
  };

  stage(kbeg, 0);
  for (int kt = kbeg; kt < kend; kt += 64){
    __syncthreads();                      // tile kt (buf0) resident
    if (kt + 32 < kend) stage(kt + 32, 1);
    compute(0);
    __syncthreads();                      // tile kt+32 (buf1) resident
    if (kt + 64 < kend) stage(kt + 64, 0);
    compute(1);
  }

  const size_t slice_off = (size_t)ks * (size_t)(gridDim.y * 128) * ldc;
  #pragma unroll
  for (int i = 0; i < 4; i++){
    float atv[4];
    #pragma unroll
    for (int r = 0; r < 4; r++){
      float a = at[m0 + wr * 64 + i * 16 + q * 4 + r];
      atv[r] = at_mode ? sqrtf(a + 1.f) : a;
    }
    float p[4] = {0.f, 0.f, 0.f, 0.f};
    #pragma unroll
    for (int j = 0; j < 4; j++){
      int col = n0 + wc * 64 + j * 16 + l15;
      float b0v = b0[col];
      float bv;
      if (mode == 0) bv = (col < 1024) ? bias_a[col] : (col < 2048) ? bias_b[col - 1024] : bias_c[col - 2048];
      else bv = bias_a[col];
      #pragma unroll
      for (int r = 0; r < 4; r++){
        size_t row = (size_t)(m0 + wr * 64 + i * 16 + q * 4 + r);
        float add = (ks == 0) ? (atv[r] * b0v + bv) : 0.f;
        float v = acc[i][j][r] + add;
        if (mode == 2) v = fmaxf(v, 0.f);
        Cbf[slice_off + row * ldc + col] = f2bf(v);
        if (mode != 1) p[r] += v * v;
      }
    }
    if (mode != 1){
      #pragma unroll
      for (int r = 0; r < 4; r++){
        float s = p[r];
        s += __shfl_xor(s, 1, 64); s += __shfl_xor(s, 2, 64);
        s += __shfl_xor(s, 4, 64); s += __shfl_xor(s, 8, 64);
        if (l15 == 0){
          int row = m0 + wr * 64 + i * 16 + q * 4 + r;
          if (mode == 2){
            atomicAdd(&rowsq[row], s);
          } else {
            int ch = (n0 + wc * 64) >> 6;       // head-chunk 0..47
            int bb = row >> 10, sidx = row & 1023;
            float t = sqrtf(s + 1.f);
            if (ch < 16)      qtv[((size_t)bb * 16 + ch) * 1024 + sidx] = t;
            else if (ch < 32) ktv[((size_t)bb * 16 + ch - 16) * 1024 + sidx] = t;
            else              vtm[((size_t)bb * 16 + ch - 32) * 1024 + sidx] = t;
          }
        }
      }
    }
  }
}

// ---------------------------------------------------------------- flash attention
// grid (S/128, B*H); 512 threads / 8 waves; wave w owns 16 q-rows of a 128-row
// Q tile. Online softmax (softmax denom cancels in lorentz normalize).
// Epilogue atomicAdds sum(out_space^2) per token into aot_sq.
__global__ __launch_bounds__(512) void attn_kernel(
    const u16* __restrict__ qkv, const float* __restrict__ qt,
    const float* __restrict__ ktm, const u16* __restrict__ vT,
    u16* __restrict__ aout, float* __restrict__ aot_sq)
{
  __shared__ u16 Qlds[8192];   // 128 rows x 8 chunks, rotated slots
  __shared__ u16 Klds[4096];   // 64 rows x 8 chunks
  __shared__ u16 Vlds[5120];   // 80 rows x 8 chunks (rows 65..79 garbage, unused cols)
  __shared__ u16 Plds[9216];   // 8 waves x 16 x 72
  const int tid = threadIdx.x;
  const int w = tid >> 6, l = tid & 63;
  const int l15 = l & 15, qd = l >> 4;
  const int q0 = blockIdx.x * 128;
  const int bh = blockIdx.y;
  const int b = bh >> 4, h = bh & 15;
  const size_t tokbase = (size_t)b << 10;

  #pragma unroll
  for (int i = 0; i < 2; i++){
    int c = i * 512 + w * 64 + l;                 // chunk slot 0..1023
    int row = c >> 3, kc = ((c & 7) - row) & 7;   // slot = row*8+((kc+row)&7)
    gl_lds16(qkv + (tokbase + q0 + row) * 3072 + h * 64 + kc * 8, &Qlds[(i * 512 + w * 64) * 8]);
  }
  __syncthreads();
  bf16x8 aq[2];
  {
    int row = w * 16 + l15;
    #pragma unroll
    for (int kk = 0; kk < 2; kk++)
      aq[kk] = *(const bf16x8*)&Qlds[(row * 8 + ((kk * 4 + qd + row) & 7)) * 8];
  }
  float tq[4];
  #pragma unroll
  for (int r = 0; r < 4; r++)
    tq[r] = qt[(size_t)bh * SEQ + q0 + w * 16 + qd * 4 + r];

  float mrow[4] = {-1e30f, -1e30f, -1e30f, -1e30f};
  f32x4 acco[5] = {};

  for (int kt = 0; kt < 16; kt++){
    __syncthreads();
    {
      int c = w * 64 + l;                         // 512 chunks
      int row = c >> 3, kc = ((c & 7) - row) & 7;
      gl_lds16(qkv + (tokbase + kt * 64 + row) * 3072 + 1024 + h * 64 + kc * 8, &Klds[w * 512]);
      gl_lds16(vT + ((size_t)bh * 65 + row) * 1024 + kt * 64 + kc * 8, &Vlds[w * 512]);
    }
    if (w == 0 && l < 8){                          // vT row 64: slots 512..519
      gl_lds16(vT + ((size_t)bh * 65 + 64) * 1024 + kt * 64 + (l & 7) * 8, &Vlds[4096]);
    }
    __syncthreads();

    float sc[4][4];
    float mx[4] = {-1e30f, -1e30f, -1e30f, -1e30f};
    #pragma unroll
    for (int ct = 0; ct < 4; ct++){
      f32x4 z = {0.f, 0.f, 0.f, 0.f};
      int key = ct * 16 + l15;
      #pragma unroll
      for (int kk = 0; kk < 2; kk++){
        bf16x8 bk = *(const bf16x8*)&Klds[(key * 8 + ((kk * 4 + qd + key) & 7)) * 8];
        z = __builtin_amdgcn_mfma_f32_16x16x32_bf16(aq[kk], bk, z, 0, 0, 0);
      }
      float tk = ktm[(size_t)bh * SEQ + kt * 64 + key];
      #pragma unroll
      for (int r = 0; r < 4; r++){
        float s = 0.25f + 0.25f * (z[r] - tq[r] * tk);
        sc[ct][r] = s;
        mx[r] = fmaxf(mx[r], s);
      }
    }
    #pragma unroll
    for (int r = 0; r < 4; r++){
      #pragma unroll
      for (int msk = 1; msk < 16; msk <<= 1)
        mx[r] = fmaxf(mx[r], __shfl_xor(mx[r], msk, 64));
      float mnew = fmaxf(mrow[r], mx[r]);
      float alpha = __expf(mrow[r] - mnew);
      mrow[r] = mnew;
      #pragma unroll
      for (int co = 0; co < 5; co++) acco[co][r] *= alpha;
      mx[r] = mnew;
    }
    #pragma unroll
    for (int ct = 0; ct < 4; ct++)
      #pragma unroll
      for (int r = 0; r < 4; r++)
        Plds[w * 1152 + (qd * 4 + r) * 72 + ct * 16 + l15] = f2bf(__expf(sc[ct][r] - mx[r]));
    asm volatile("s_waitcnt lgkmcnt(0)" ::: "memory");
    bf16x8 ap[2];
    #pragma unroll
    for (int kk = 0; kk < 2; kk++)
      ap[kk] = *(const bf16x8*)&Plds[w * 1152 + l15 * 72 + kk * 32 + qd * 8];
    #pragma unroll
    for (int co = 0; co < 5; co++){
      int vtr = co * 16 + l15;
      #pragma unroll
      for (int kk = 0; kk < 2; kk++){
        bf16x8 bv = *(const bf16x8*)&Vlds[(vtr * 8 + ((kk * 4 + qd + vtr) & 7)) * 8];
        acco[co] = __builtin_amdgcn_mfma_f32_16x16x32_bf16(ap[kk], bv, acco[co], 0, 0, 0);
      }
    }
  }
  #pragma unroll
  for (int r = 0; r < 4; r++){
    float ss = 0.f;
    #pragma unroll
    for (int co = 0; co < 5; co++){
      int col = co * 16 + l15;
      float v = acco[co][r];
      if (col == 0) ss -= v * v;
      else if (col < 65) ss += v * v;
    }
    #pragma unroll
    for (int msk = 1; msk < 16; msk <<= 1) ss += __shfl_xor(ss, msk, 64);
    float v0b = __shfl(acco[0][r], l & 48, 64);       // time comp broadcast in 16-group
    float sp = ss + v0b * v0b;                        // sum of space^2
    float rn = rsqrtf(fmaxf(fabsf(ss), 1e-8f));
    size_t rowg = tokbase + q0 + w * 16 + qd * 4 + r;
    if (l15 == 0) atomicAdd(&aot_sq[rowg], sp * rn * rn);
    #pragma unroll
    for (int co = 0; co < 5; co++){
      int col = co * 16 + l15;
      if (col >= 1 && col < 65)
        aout[rowg * 1024 + h * 64 + col - 1] = f2bf(acco[co][r] * rn);
    }
  }
}

// ---------------------------------------------------------------- midpoint + hyp_layernorm
__device__ __forceinline__ float block_sum(float v, float* red){
  int tid = threadIdx.x;
  #pragma unroll
  for (int m = 1; m < 64; m <<= 1) v += __shfl_xor(v, m, 64);
  __syncthreads();
  if ((tid & 63) == 0) red[tid >> 6] = v;
  __syncthreads();
  return red[0] + red[1] + red[2] + red[3];
}

__global__ __launch_bounds__(256) void mid_ln(
    const u16* __restrict__ z, const float* __restrict__ xfull,
    const u16* __restrict__ xsb, const float* __restrict__ xtv,
    const float* __restrict__ gam, const float* __restrict__ bet,
    u16* __restrict__ ob, float* __restrict__ ot,
    float* __restrict__ ofull, int mode_x, int mode_out, int nsl)
{
  __shared__ float red[4];
  const int tid = threadIdx.x;
  const int tok = blockIdx.x;
  float zv[4], xv[4], xtime;
  if (mode_x == 0){
    const float* xr = xfull + (size_t)tok * 1025;
    xtime = xr[0];
    #pragma unroll
    for (int j = 0; j < 4; j++) xv[j] = xr[1 + tid + j * 256];
  } else {
    xtime = xtv[tok];
    const u16* xr = xsb + (size_t)tok * 1024;
    #pragma unroll
    for (int j = 0; j < 4; j++) xv[j] = bf2f(xr[tid + j * 256]);
  }
  // sum split-K bf16 slices of z
  {
    #pragma unroll
    for (int j = 0; j < 4; j++) zv[j] = 0.f;
    for (int s = 0; s < nsl; s++){
      const u16* zs = z + (size_t)s * NTOK * 1024 + (size_t)tok * 1024;
      #pragma unroll
      for (int j = 0; j < 4; j++) zv[j] += bf2f(zs[tid + j * 256]);
    }
  }
  float ssz = 0.f;
  #pragma unroll
  for (int j = 0; j < 4; j++) ssz += zv[j] * zv[j];
  ssz = block_sum(ssz, red);
  float tz = sqrtf(ssz + 1.f);
  float av[4]; float ssa = 0.f;
  #pragma unroll
  for (int j = 0; j < 4; j++){ av[j] = 0.5f * (zv[j] + xv[j]); ssa += av[j] * av[j]; }
  ssa = block_sum(ssa, red);
  float avt = 0.5f * (tz + xtime);
  float rn = rsqrtf(fmaxf(fabsf(ssa - avt * avt), 1e-8f));
  float uv[4]; float su = 0.f, squ = 0.f;
  #pragma unroll
  for (int j = 0; j < 4; j++){ uv[j] = av[j] * rn; su += uv[j]; squ += uv[j] * uv[j]; }
  su = block_sum(su, red);
  squ = block_sum(squ, red);
  float mu = su * (1.f / 1024.f);
  float var = squ * (1.f / 1024.f) - mu * mu;
  float rv = rsqrtf(fmaxf(var, 0.f) + 1e-5f);
  float sv[4]; float sss = 0.f;
  #pragma unroll
  for (int j = 0; j < 4; j++){
    int i = tid + j * 256;
    sv[j] = (uv[j] - mu) * rv * gam[i] + bet[i];
    sss += sv[j] * sv[j];
  }
  sss = block_sum(sss, red);
  float tout = sqrtf(sss + 1.f);
  if (mode_out == 0){
    #pragma unroll
    for (int j = 0; j < 4; j++){
      int i = tid + j * 256;
      ob[(size_t)tok * 1024 + i] = f2bf(sv[j]);
    }
    if (tid == 0) ot[tok] = tout;
  } else {
    float* orow = ofull + (size_t)tok * 1025;
    #pragma unroll
    for (int j = 0; j < 4; j++) orow[1 + tid + j * 256] = sv[j];
    if (tid == 0) orow[0] = tout;
  }
}

// ---------------------------------------------------------------- launch
extern "C" void kernel_launch(void* const* d_in, const int* in_sizes, int n_in,
                              void* d_out, int out_size, void* d_ws, size_t ws_size,
                              hipStream_t stream){
  const float* x   = (const float*)d_in[0];
  const float* Wq  = (const float*)d_in[1];
  const float* bq  = (const float*)d_in[2];
  const float* Wk  = (const float*)d_in[3];
  const float* bk  = (const float*)d_in[4];
  const float* Wv  = (const float*)d_in[5];
  const float* bv  = (const float*)d_in[6];
  const float* Wo  = (const float*)d_in[7];
  const float* bo  = (const float*)d_in[8];
  const float* g1  = (const float*)d_in[9];
  const float* be1 = (const float*)d_in[10];
  const float* W1  = (const float*)d_in[11];
  const float* c1  = (const float*)d_in[12];
  const float* W2  = (const float*)d_in[13];
  const float* c2  = (const float*)d_in[14];
  const float* g2  = (const float*)d_in[15];
  const float* be2 = (const float*)d_in[16];
  float* out = (float*)d_out;

  char* p = (char*)d_ws;
  auto take = [&](size_t n){ char* r = p; p += (n + 255) & ~(size_t)255; return r; };
  u16*   xs    = (u16*)  take((size_t)NTOK * 1024 * 2);
  float* xt    = (float*)take(NTOK * 4);
  u16*   wqkv  = (u16*)  take((size_t)3072 * 1024 * 2);
  float* wqkv0 = (float*)take(3072 * 4);
  u16*   wo_s  = (u16*)  take((size_t)1024 * 1024 * 2);
  float* wo0   = (float*)take(1024 * 4);
  u16*   w1_s  = (u16*)  take((size_t)4096 * 1024 * 2);
  float* w10   = (float*)take(4096 * 4);
  u16*   w2_s  = (u16*)  take((size_t)1024 * 4096 * 2);
  float* w20   = (float*)take(1024 * 4);
  u16*   qkvb  = (u16*)  take((size_t)NTOK * 3072 * 2);
  float* qtv   = (float*)take((size_t)64 * 1024 * 4);
  float* ktv   = (float*)take((size_t)64 * 1024 * 4);
  float* vtm   = (float*)take((size_t)64 * 1024 * 4);
  u16*   vT    = (u16*)  take((size_t)64 * 65 * 1024 * 2);
  u16*   aoutb = (u16*)  take((size_t)NTOK * 1024 * 2);
  float* sqbuf = (float*)take((size_t)2 * NTOK * 4);   // aot_sq | htv_sq (one memset)
  float* aot_sq = sqbuf;
  float* htv_sq = sqbuf + NTOK;
  u16*   zbuf  = (u16*)  take((size_t)4 * NTOK * 1024 * 2);   // 4 split-K bf16 slices
  u16*   x1b   = (u16*)  take((size_t)NTOK * 1024 * 2);
  float* x1t   = (float*)take(NTOK * 4);
  u16*   hbuf  = (u16*)  take((size_t)NTOK * 4096 * 2);

  hipMemsetAsync(sqbuf, 0, (size_t)2 * NTOK * 4, stream);

  conv_x<<<NTOK * 1024 / 256, 256, 0, stream>>>(x, xs, xt);
  conv_w_all<<<(12 * 1024 * 1024) / 256, 256, 0, stream>>>(
      Wq, Wk, Wv, Wo, W1, W2, wqkv, wo_s, w1_s, w2_s, wqkv0, wo0, w10, w20);

  // QKV + fused per-head time norms
  gemm_bt<<<dim3(24, 32), 256, 0, stream>>>(xs, 1024, wqkv, 1024, xt, 0, wqkv0,
      bq, bk, bv, qkvb, 3072, 1024, 0, qtv, ktv, vtm, nullptr);
  v_transpose<<<dim3(16, 64), 256, 0, stream>>>(qkvb, vtm, vT);
  attn_kernel<<<dim3(8, 64), 512, 0, stream>>>(qkvb, qtv, ktv, vT, aoutb, aot_sq);
  // O-proj: split-K x2, bf16 partial slices
  gemm_bt<<<dim3(8, 32, 2), 256, 0, stream>>>(aoutb, 1024, wo_s, 1024, aot_sq, 1, wo0,
      bo, nullptr, nullptr, zbuf, 1024, 512, 1, nullptr, nullptr, nullptr, nullptr);
  mid_ln<<<NTOK, 256, 0, stream>>>(zbuf, x, nullptr, nullptr, g1, be1,
      x1b, x1t, nullptr, 0, 0, 2);
  // MLP1 + relu + fused row sum-of-squares
  gemm_bt<<<dim3(32, 32), 256, 0, stream>>>(x1b, 1024, w1_s, 1024, x1t, 0, w10,
      c1, nullptr, nullptr, hbuf, 4096, 1024, 2, nullptr, nullptr, nullptr, htv_sq);
  // MLP2: split-K x4, bf16 partial slices
  gemm_bt<<<dim3(8, 32, 4), 256, 0, stream>>>(hbuf, 4096, w2_s, 4096, htv_sq, 1, w20,
      c2, nullptr, nullptr, zbuf, 1024, 1024, 1, nullptr, nullptr, nullptr, nullptr);
  mid_ln<<<NTOK, 256, 0, stream>>>(zbuf, nullptr, x1b, x1t, g2, be2,
      nullptr, nullptr, out, 1, 1, 4);
}

// Round 7
// 431.208 us; speedup vs baseline: 5.0714x; 1.0396x over previous
//
#include <hip/hip_runtime.h>

typedef unsigned short u16;
typedef unsigned int   u32;
typedef short bf16x8 __attribute__((ext_vector_type(8)));
typedef float f32x4  __attribute__((ext_vector_type(4)));

#define NTOK 4096   // B*S
#define SEQ  1024

__device__ __forceinline__ u16 f2bf(float f){
  union { float f; u32 u; } x; x.f = f;
  u32 r = (x.u + 0x7FFFu + ((x.u >> 16) & 1u)) >> 16;
  return (u16)r;
}
__device__ __forceinline__ float bf2f(u16 u){
  union { u32 u; float f; } x; x.u = ((u32)u) << 16; return x.f;
}
__device__ __forceinline__ void gl_lds16(const void* gp, void* lp){
  __builtin_amdgcn_global_load_lds(
      (const __attribute__((address_space(1))) u32*)gp,
      (__attribute__((address_space(3))) u32*)lp, 16, 0, 0);
}

// ---------------------------------------------------------------- converts
__global__ __launch_bounds__(256) void conv_x(const float* __restrict__ x,
                                              u16* __restrict__ xs, float* __restrict__ xt){
  int t = blockIdx.x * 256 + threadIdx.x;        // < NTOK*1024
  int tok = t >> 10, i = t & 1023;
  xs[t] = f2bf(x[(size_t)tok * 1025 + 1 + i]);
  if (i == 0) xt[tok] = x[(size_t)tok * 1025];
}

// all six weight converts in one launch; region branches are wave-uniform
__global__ __launch_bounds__(256) void conv_w_all(
    const float* __restrict__ Wq, const float* __restrict__ Wk,
    const float* __restrict__ Wv, const float* __restrict__ Wo,
    const float* __restrict__ W1, const float* __restrict__ W2,
    u16* __restrict__ wqkv, u16* __restrict__ wo_s, u16* __restrict__ w1_s, u16* __restrict__ w2_s,
    float* __restrict__ wqkv0, float* __restrict__ wo0, float* __restrict__ w10, float* __restrict__ w20)
{
  int t = blockIdx.x * 256 + threadIdx.x;   // < 12*1024*1024
  const int M1 = 1 << 20;
  const float* W; u16* Wb; float* w0; int shift; int idx;
  if (t < 4 * M1){
    int region = t >> 20; idx = t & (M1 - 1); shift = 10;
    if (region == 0)      { W = Wq; Wb = wqkv;          w0 = wqkv0; }
    else if (region == 1) { W = Wk; Wb = wqkv + M1;     w0 = wqkv0 + 1024; }
    else if (region == 2) { W = Wv; Wb = wqkv + 2 * M1; w0 = wqkv0 + 2048; }
    else                  { W = Wo; Wb = wo_s;          w0 = wo0; }
  } else if (t < 8 * M1){
    idx = t - 4 * M1; shift = 10; W = W1; Wb = w1_s; w0 = w10;
  } else {
    idx = t - 8 * M1; shift = 12; W = W2; Wb = w2_s; w0 = w20;
  }
  int Kin = 1 << shift;
  int r = idx >> shift, i = idx & (Kin - 1);
  Wb[idx] = f2bf(W[(size_t)r * (Kin + 1) + 1 + i]);
  if (i == 0) w0[r] = W[(size_t)r * (Kin + 1)];
}

// ---------------------------------------------------------------- V transpose (time row from vtm)
// out: vT[(bh*65 + r)*1024 + key]; r=0 is t_v, r=1..64 are feats 0..63
__global__ __launch_bounds__(256) void v_transpose(const u16* __restrict__ qkv,
                                                   const float* __restrict__ vtm,
                                                   u16* __restrict__ vT){
  __shared__ u16 tile[64 * 72];
  const int tid = threadIdx.x;
  const int kt = blockIdx.x, bh = blockIdx.y;
  const int b = bh >> 4, h = bh & 15;
  #pragma unroll
  for (int i = 0; i < 2; i++){
    int c = tid * 2 + i;                          // 0..511
    int key = c >> 3, fc = c & 7;
    uint4 v = *(const uint4*)(qkv + ((size_t)(b * 1024 + kt * 64 + key)) * 3072 + 2048 + h * 64 + fc * 8);
    *(uint4*)&tile[key * 72 + fc * 8] = v;
  }
  __syncthreads();
  for (int c = tid; c < 520; c += 256){
    int vtr = c >> 3, kc = c & 7;
    union { uint4 v; u16 s[8]; } d;
    if (vtr == 0){
      #pragma unroll
      for (int j = 0; j < 8; j++) d.s[j] = f2bf(vtm[(size_t)bh * 1024 + kt * 64 + kc * 8 + j]);
    } else {
      int f = vtr - 1;
      #pragma unroll
      for (int j = 0; j < 8; j++) d.s[j] = tile[(kc * 8 + j) * 72 + f];
    }
    *(uint4*)(vT + ((size_t)bh * 65 + vtr) * 1024 + kt * 64 + kc * 8) = d.v;
  }
}

// ---------------------------------------------------------------- GEMM: C = A(MxK) * B(NxK)^T + at[m]*b0[n] + bias[n]
// BK=64 double-buffer: each buffer holds two swizzled 32-K halves; one barrier
// per 64-K (16 barriers at K=1024 vs 32 before). LDS 64 KB -> 2 blocks/CU (the
// capacity we already had). Kslice must be a multiple of 128.
// at_mode: 0 -> atv=at[m]; 1 -> atv=sqrt(at[m]+1)
// mode 0: QKV (segmented bias, fused per-head time write to qtv/ktv/vtm)
// mode 1: bf16 out at slice offset (split-K partials; bias only on slice 0)
// mode 2: relu -> bf16 out, fused row sum-of-squares atomicAdd into rowsq
__global__ __launch_bounds__(256) void gemm_bt(
    const u16* __restrict__ A, int lda, const u16* __restrict__ Bm, int ldb,
    const float* __restrict__ at, int at_mode, const float* __restrict__ b0,
    const float* __restrict__ bias_a, const float* __restrict__ bias_b, const float* __restrict__ bias_c,
    u16* __restrict__ Cbf, int ldc, int Kslice, int mode,
    float* __restrict__ qtv, float* __restrict__ ktv, float* __restrict__ vtm,
    float* __restrict__ rowsq)
{
  __shared__ u16 As[2][128 * 64];
  __shared__ u16 Bs[2][128 * 64];
  const int tid = threadIdx.x;
  const int w = tid >> 6, l = tid & 63;
  const int l15 = l & 15, q = l >> 4;
  const int m0 = blockIdx.y * 128, n0 = blockIdx.x * 128;
  const int ks = blockIdx.z;
  const int kbeg = ks * Kslice;
  const int kend = kbeg + Kslice;
  const int wr = w >> 1, wc = w & 1;
  f32x4 acc[4][4] = {};

  auto stage = [&](int kt, int buf){               // stage 64-K (two halves)
    #pragma unroll
    for (int half = 0; half < 2; half++){
      #pragma unroll
      for (int i = 0; i < 2; i++){
        int s = (w * 2 + i) * 64 + l;              // LDS slot 0..511
        int row = s >> 2;
        int kc = ((s & 3) - (s >> 3)) & 3;         // invert swizzle
        gl_lds16(A  + (size_t)(m0 + row) * lda + kt + half * 32 + kc * 8,
                 &As[buf][half * 4096 + (w * 2 + i) * 512]);
        gl_lds16(Bm + (size_t)(n0 + row) * ldb + kt + half * 32 + kc * 8,
                 &Bs[buf][half * 4096 + (w * 2 + i) * 512]);
      }
    }
  };
  auto compute = [&](int buf, int half){
    bf16x8 af[4], bfr[4];
    #pragma unroll
    for (int i = 0; i < 4; i++){
      int row = wr * 64 + i * 16 + l15;
      int slot = row * 4 + ((q + (row >> 1)) & 3);
      af[i] = *(const bf16x8*)&As[buf][half * 4096 + slot * 8];
    }
    #pragma unroll
    for (int j = 0; j < 4; j++){
      int row = wc * 64 + j * 16 + l15;
      int slot = row * 4 + ((q + (row >> 1)) & 3);
      bfr[j] = *(const bf16x8*)&Bs[buf][half * 4096 + slot * 8];
    }
    #pragma unroll
    for (int i = 0; i < 4; i++)
      #pragma unroll
      for (int j = 0; j < 4; j++)
        acc[i][j] = __builtin_amdgcn_mfma_f32_16x16x32_bf16(af[i], bfr[j], acc[i][j], 0, 0, 0);
  };

  stage(kbeg, 0);
  for (int kt = kbeg; kt < kend; kt += 128){
    __syncthreads();                      // buf0 (kt..kt+64) resident
    if (kt + 64 < kend) stage(kt + 64, 1);
    compute(0, 0); compute(0, 1);
    __syncthreads();                      // buf1 resident
    if (kt + 128 < kend) stage(kt + 128, 0);
    compute(1, 0); compute(1, 1);
  }

  const size_t slice_off = (size_t)ks * (size_t)(gridDim.y * 128) * ldc;
  #pragma unroll
  for (int i = 0; i < 4; i++){
    float atv[4];
    #pragma unroll
    for (int r = 0; r < 4; r++){
      float a = at[m0 + wr * 64 + i * 16 + q * 4 + r];
      atv[r] = at_mode ? sqrtf(a + 1.f) : a;
    }
    float p[4] = {0.f, 0.f, 0.f, 0.f};
    #pragma unroll
    for (int j = 0; j < 4; j++){
      int col = n0 + wc * 64 + j * 16 + l15;
      float b0v = b0[col];
      float bv;
      if (mode == 0) bv = (col < 1024) ? bias_a[col] : (col < 2048) ? bias_b[col - 1024] : bias_c[col - 2048];
      else bv = bias_a[col];
      #pragma unroll
      for (int r = 0; r < 4; r++){
        size_t row = (size_t)(m0 + wr * 64 + i * 16 + q * 4 + r);
        float add = (ks == 0) ? (atv[r] * b0v + bv) : 0.f;
        float v = acc[i][j][r] + add;
        if (mode == 2) v = fmaxf(v, 0.f);
        Cbf[slice_off + row * ldc + col] = f2bf(v);
        if (mode != 1) p[r] += v * v;
      }
    }
    if (mode != 1){
      #pragma unroll
      for (int r = 0; r < 4; r++){
        float s = p[r];
        s += __shfl_xor(s, 1, 64); s += __shfl_xor(s, 2, 64);
        s += __shfl_xor(s, 4, 64); s += __shfl_xor(s, 8, 64);
        if (l15 == 0){
          int row = m0 + wr * 64 + i * 16 + q * 4 + r;
          if (mode == 2){
            atomicAdd(&rowsq[row], s);
          } else {
            int ch = (n0 + wc * 64) >> 6;       // head-chunk 0..47
            int bb = row >> 10, sidx = row & 1023;
            float t = sqrtf(s + 1.f);
            if (ch < 16)      qtv[((size_t)bb * 16 + ch) * 1024 + sidx] = t;
            else if (ch < 32) ktv[((size_t)bb * 16 + ch - 16) * 1024 + sidx] = t;
            else              vtm[((size_t)bb * 16 + ch - 32) * 1024 + sidx] = t;
          }
        }
      }
    }
  }
}

// ---------------------------------------------------------------- flash attention
// grid (S/128, B*H); 512 threads / 8 waves; wave w owns 16 q-rows of a 128-row
// Q tile. K/V double-buffered (one barrier per K-tile); V buf1 reuses the dead
// Q staging region. Online softmax (denom cancels in lorentz normalize).
// Epilogue atomicAdds sum(out_space^2) per token into aot_sq.
__global__ __launch_bounds__(512) void attn_kernel(
    const u16* __restrict__ qkv, const float* __restrict__ qt,
    const float* __restrict__ ktm, const u16* __restrict__ vT,
    u16* __restrict__ aout, float* __restrict__ aot_sq)
{
  __shared__ u16 smem[30720];   // 61440 B
  u16* Qlds = smem;                                   // [0,8192) prologue only
  u16* Kl0 = smem + 8192;                             // [8192,12288)
  u16* Kl1 = smem + 12288;                            // [12288,16384)
  u16* Vl0 = smem + 16384;                            // [16384,21504) 5120
  u16* Vl1 = smem;                                    // reuse Q region (5120)
  u16* Plds = smem + 21504;                           // [21504,30720) 9216
  const int tid = threadIdx.x;
  const int w = tid >> 6, l = tid & 63;
  const int l15 = l & 15, qd = l >> 4;
  const int q0 = blockIdx.x * 128;
  const int bh = blockIdx.y;
  const int b = bh >> 4, h = bh & 15;
  const size_t tokbase = (size_t)b << 10;

  #pragma unroll
  for (int i = 0; i < 2; i++){
    int c = i * 512 + w * 64 + l;                 // chunk slot 0..1023
    int row = c >> 3, kc = ((c & 7) - row) & 7;   // slot = row*8+((kc+row)&7)
    gl_lds16(qkv + (tokbase + q0 + row) * 3072 + h * 64 + kc * 8, &Qlds[(i * 512 + w * 64) * 8]);
  }
  __syncthreads();
  bf16x8 aq[2];
  {
    int row = w * 16 + l15;
    #pragma unroll
    for (int kk = 0; kk < 2; kk++)
      aq[kk] = *(const bf16x8*)&Qlds[(row * 8 + ((kk * 4 + qd + row) & 7)) * 8];
  }
  float tq[4];
  #pragma unroll
  for (int r = 0; r < 4; r++)
    tq[r] = qt[(size_t)bh * SEQ + q0 + w * 16 + qd * 4 + r];

  auto stage_kv = [&](int kt, int buf){
    u16* K = buf ? Kl1 : Kl0;
    u16* V = buf ? Vl1 : Vl0;
    int c = w * 64 + l;                           // 512 chunks
    int row = c >> 3, kc = ((c & 7) - row) & 7;
    gl_lds16(qkv + (tokbase + kt * 64 + row) * 3072 + 1024 + h * 64 + kc * 8, &K[w * 512]);
    gl_lds16(vT + ((size_t)bh * 65 + row) * 1024 + kt * 64 + kc * 8, &V[w * 512]);
    if (w == 0 && l < 8)                          // vT row 64: slots 512..519
      gl_lds16(vT + ((size_t)bh * 65 + 64) * 1024 + kt * 64 + (l & 7) * 8, &V[4096]);
  };

  float mrow[4] = {-1e30f, -1e30f, -1e30f, -1e30f};
  f32x4 acco[5] = {};

  stage_kv(0, 0);                                 // Q region untouched here
  for (int kt = 0; kt < 16; kt++){
    __syncthreads();    // buf(kt&1) K/V resident; (kt=0) all aq reads drained
    if (kt + 1 < 16) stage_kv(kt + 1, (kt + 1) & 1);
    u16* K = (kt & 1) ? Kl1 : Kl0;
    u16* V = (kt & 1) ? Vl1 : Vl0;

    float sc[4][4];
    float mx[4] = {-1e30f, -1e30f, -1e30f, -1e30f};
    #pragma unroll
    for (int ct = 0; ct < 4; ct++){
      f32x4 z = {0.f, 0.f, 0.f, 0.f};
      int key = ct * 16 + l15;
      #pragma unroll
      for (int kk = 0; kk < 2; kk++){
        bf16x8 bk = *(const bf16x8*)&K[(key * 8 + ((kk * 4 + qd + key) & 7)) * 8];
        z = __builtin_amdgcn_mfma_f32_16x16x32_bf16(aq[kk], bk, z, 0, 0, 0);
      }
      float tk = ktm[(size_t)bh * SEQ + kt * 64 + key];
      #pragma unroll
      for (int r = 0; r < 4; r++){
        float s = 0.25f + 0.25f * (z[r] - tq[r] * tk);
        sc[ct][r] = s;
        mx[r] = fmaxf(mx[r], s);
      }
    }
    #pragma unroll
    for (int r = 0; r < 4; r++){
      #pragma unroll
      for (int msk = 1; msk < 16; msk <<= 1)
        mx[r] = fmaxf(mx[r], __shfl_xor(mx[r], msk, 64));
      float mnew = fmaxf(mrow[r], mx[r]);
      float alpha = __expf(mrow[r] - mnew);
      mrow[r] = mnew;
      #pragma unroll
      for (int co = 0; co < 5; co++) acco[co][r] *= alpha;
      mx[r] = mnew;
    }
    #pragma unroll
    for (int ct = 0; ct < 4; ct++)
      #pragma unroll
      for (int r = 0; r < 4; r++)
        Plds[w * 1152 + (qd * 4 + r) * 72 + ct * 16 + l15] = f2bf(__expf(sc[ct][r] - mx[r]));
    asm volatile("s_waitcnt lgkmcnt(0)" ::: "memory");
    bf16x8 ap[2];
    #pragma unroll
    for (int kk = 0; kk < 2; kk++)
      ap[kk] = *(const bf16x8*)&Plds[w * 1152 + l15 * 72 + kk * 32 + qd * 8];
    #pragma unroll
    for (int co = 0; co < 5; co++){
      int vtr = co * 16 + l15;
      #pragma unroll
      for (int kk = 0; kk < 2; kk++){
        bf16x8 bv = *(const bf16x8*)&V[(vtr * 8 + ((kk * 4 + qd + vtr) & 7)) * 8];
        acco[co] = __builtin_amdgcn_mfma_f32_16x16x32_bf16(ap[kk], bv, acco[co], 0, 0, 0);
      }
    }
  }
  #pragma unroll
  for (int r = 0; r < 4; r++){
    float ss = 0.f;
    #pragma unroll
    for (int co = 0; co < 5; co++){
      int col = co * 16 + l15;
      float v = acco[co][r];
      if (col == 0) ss -= v * v;
      else if (col < 65) ss += v * v;
    }
    #pragma unroll
    for (int msk = 1; msk < 16; msk <<= 1) ss += __shfl_xor(ss, msk, 64);
    float v0b = __shfl(acco[0][r], l & 48, 64);       // time comp broadcast in 16-group
    float sp = ss + v0b * v0b;                        // sum of space^2
    float rn = rsqrtf(fmaxf(fabsf(ss), 1e-8f));
    size_t rowg = tokbase + q0 + w * 16 + qd * 4 + r;
    if (l15 == 0) atomicAdd(&aot_sq[rowg], sp * rn * rn);
    #pragma unroll
    for (int co = 0; co < 5; co++){
      int col = co * 16 + l15;
      if (col >= 1 && col < 65)
        aout[rowg * 1024 + h * 64 + col - 1] = f2bf(acco[co][r] * rn);
    }
  }
}

// ---------------------------------------------------------------- midpoint + hyp_layernorm
__device__ __forceinline__ float block_sum(float v, float* red){
  int tid = threadIdx.x;
  #pragma unroll
  for (int m = 1; m < 64; m <<= 1) v += __shfl_xor(v, m, 64);
  __syncthreads();
  if ((tid & 63) == 0) red[tid >> 6] = v;
  __syncthreads();
  return red[0] + red[1] + red[2] + red[3];
}

__global__ __launch_bounds__(256) void mid_ln(
    const u16* __restrict__ z, const u16* __restrict__ xsb, const float* __restrict__ xtv,
    const float* __restrict__ gam, const float* __restrict__ bet,
    u16* __restrict__ ob, float* __restrict__ ot,
    float* __restrict__ ofull, int mode_out, int nsl)
{
  __shared__ float red[4];
  const int tid = threadIdx.x;
  const int tok = blockIdx.x;
  float zv[4], xv[4], xtime;
  xtime = xtv[tok];
  {
    const u16* xr = xsb + (size_t)tok * 1024;
    #pragma unroll
    for (int j = 0; j < 4; j++) xv[j] = bf2f(xr[tid + j * 256]);
  }
  // sum split-K bf16 slices of z
  {
    #pragma unroll
    for (int j = 0; j < 4; j++) zv[j] = 0.f;
    for (int s = 0; s < nsl; s++){
      const u16* zs = z + (size_t)s * NTOK * 1024 + (size_t)tok * 1024;
      #pragma unroll
      for (int j = 0; j < 4; j++) zv[j] += bf2f(zs[tid + j * 256]);
    }
  }
  float ssz = 0.f;
  #pragma unroll
  for (int j = 0; j < 4; j++) ssz += zv[j] * zv[j];
  ssz = block_sum(ssz, red);
  float tz = sqrtf(ssz + 1.f);
  float av[4]; float ssa = 0.f;
  #pragma unroll
  for (int j = 0; j < 4; j++){ av[j] = 0.5f * (zv[j] + xv[j]); ssa += av[j] * av[j]; }
  ssa = block_sum(ssa, red);
  float avt = 0.5f * (tz + xtime);
  float rn = rsqrtf(fmaxf(fabsf(ssa - avt * avt), 1e-8f));
  float uv[4]; float su = 0.f, squ = 0.f;
  #pragma unroll
  for (int j = 0; j < 4; j++){ uv[j] = av[j] * rn; su += uv[j]; squ += uv[j] * uv[j]; }
  su = block_sum(su, red);
  squ = block_sum(squ, red);
  float mu = su * (1.f / 1024.f);
  float var = squ * (1.f / 1024.f) - mu * mu;
  float rv = rsqrtf(fmaxf(var, 0.f) + 1e-5f);
  float sv[4]; float sss = 0.f;
  #pragma unroll
  for (int j = 0; j < 4; j++){
    int i = tid + j * 256;
    sv[j] = (uv[j] - mu) * rv * gam[i] + bet[i];
    sss += sv[j] * sv[j];
  }
  sss = block_sum(sss, red);
  float tout = sqrtf(sss + 1.f);
  if (mode_out == 0){
    #pragma unroll
    for (int j = 0; j < 4; j++){
      int i = tid + j * 256;
      ob[(size_t)tok * 1024 + i] = f2bf(sv[j]);
    }
    if (tid == 0) ot[tok] = tout;
  } else {
    float* orow = ofull + (size_t)tok * 1025;
    #pragma unroll
    for (int j = 0; j < 4; j++) orow[1 + tid + j * 256] = sv[j];
    if (tid == 0) orow[0] = tout;
  }
}

// ---------------------------------------------------------------- launch
extern "C" void kernel_launch(void* const* d_in, const int* in_sizes, int n_in,
                              void* d_out, int out_size, void* d_ws, size_t ws_size,
                              hipStream_t stream){
  const float* x   = (const float*)d_in[0];
  const float* Wq  = (const float*)d_in[1];
  const float* bq  = (const float*)d_in[2];
  const float* Wk  = (const float*)d_in[3];
  const float* bk  = (const float*)d_in[4];
  const float* Wv  = (const float*)d_in[5];
  const float* bv  = (const float*)d_in[6];
  const float* Wo  = (const float*)d_in[7];
  const float* bo  = (const float*)d_in[8];
  const float* g1  = (const float*)d_in[9];
  const float* be1 = (const float*)d_in[10];
  const float* W1  = (const float*)d_in[11];
  const float* c1  = (const float*)d_in[12];
  const float* W2  = (const float*)d_in[13];
  const float* c2  = (const float*)d_in[14];
  const float* g2  = (const float*)d_in[15];
  const float* be2 = (const float*)d_in[16];
  float* out = (float*)d_out;

  char* p = (char*)d_ws;
  auto take = [&](size_t n){ char* r = p; p += (n + 255) & ~(size_t)255; return r; };
  u16*   xs    = (u16*)  take((size_t)NTOK * 1024 * 2);
  float* xt    = (float*)take(NTOK * 4);
  u16*   wqkv  = (u16*)  take((size_t)3072 * 1024 * 2);
  float* wqkv0 = (float*)take(3072 * 4);
  u16*   wo_s  = (u16*)  take((size_t)1024 * 1024 * 2);
  float* wo0   = (float*)take(1024 * 4);
  u16*   w1_s  = (u16*)  take((size_t)4096 * 1024 * 2);
  float* w10   = (float*)take(4096 * 4);
  u16*   w2_s  = (u16*)  take((size_t)1024 * 4096 * 2);
  float* w20   = (float*)take(1024 * 4);
  u16*   qkvb  = (u16*)  take((size_t)NTOK * 3072 * 2);
  float* qtv   = (float*)take((size_t)64 * 1024 * 4);
  float* ktv   = (float*)take((size_t)64 * 1024 * 4);
  float* vtm   = (float*)take((size_t)64 * 1024 * 4);
  u16*   vT    = (u16*)  take((size_t)64 * 65 * 1024 * 2);
  u16*   aoutb = (u16*)  take((size_t)NTOK * 1024 * 2);
  float* sqbuf = (float*)take((size_t)2 * NTOK * 4);   // aot_sq | htv_sq (one memset)
  float* aot_sq = sqbuf;
  float* htv_sq = sqbuf + NTOK;
  u16*   zbuf  = (u16*)  take((size_t)4 * NTOK * 1024 * 2);   // 4 split-K bf16 slices
  u16*   x1b   = (u16*)  take((size_t)NTOK * 1024 * 2);
  float* x1t   = (float*)take(NTOK * 4);
  u16*   hbuf  = (u16*)  take((size_t)NTOK * 4096 * 2);

  hipMemsetAsync(sqbuf, 0, (size_t)2 * NTOK * 4, stream);

  conv_x<<<NTOK * 1024 / 256, 256, 0, stream>>>(x, xs, xt);
  conv_w_all<<<(12 * 1024 * 1024) / 256, 256, 0, stream>>>(
      Wq, Wk, Wv, Wo, W1, W2, wqkv, wo_s, w1_s, w2_s, wqkv0, wo0, w10, w20);

  // QKV + fused per-head time norms
  gemm_bt<<<dim3(24, 32), 256, 0, stream>>>(xs, 1024, wqkv, 1024, xt, 0, wqkv0,
      bq, bk, bv, qkvb, 3072, 1024, 0, qtv, ktv, vtm, nullptr);
  v_transpose<<<dim3(16, 64), 256, 0, stream>>>(qkvb, vtm, vT);
  attn_kernel<<<dim3(8, 64), 512, 0, stream>>>(qkvb, qtv, ktv, vT, aoutb, aot_sq);
  // O-proj: split-K x2, bf16 partial slices
  gemm_bt<<<dim3(8, 32, 2), 256, 0, stream>>>(aoutb, 1024, wo_s, 1024, aot_sq, 1, wo0,
      bo, nullptr, nullptr, zbuf, 1024, 512, 1, nullptr, nullptr, nullptr, nullptr);
  mid_ln<<<NTOK, 256, 0, stream>>>(zbuf, xs, xt, g1, be1,
      x1b, x1t, nullptr, 0, 2);
  // MLP1 + relu + fused row sum-of-squares
  gemm_bt<<<dim3(32, 32), 256, 0, stream>>>(x1b, 1024, w1_s, 1024, x1t, 0, w10,
      c1, nullptr, nullptr, hbuf, 4096, 1024, 2, nullptr, nullptr, nullptr, htv_sq);
  // MLP2: split-K x4, bf16 partial slices
  gemm_bt<<<dim3(8, 32, 4), 256, 0, stream>>>(hbuf, 4096, w2_s, 4096, htv_sq, 1, w20,
      c2, nullptr, nullptr, zbuf, 1024, 1024, 1, nullptr, nullptr, nullptr, nullptr);
  mid_ln<<<NTOK, 256, 0, stream>>>(zbuf, x1b, x1t, g2, be2,
      nullptr, nullptr, out, 1, 4);
}